// Round 1
// baseline (3059.518 us; speedup 1.0000x reference)
//
#include <hip/hip_runtime.h>

// Problem constants (GraphSAGE encoder)
//   N=50000 nodes, G=2000 in-feats, E=800000 edges, H=512 hidden, Z=64 out
// Restructured: aggregate AFTER the linear maps (linearity of segment-mean).

#define BN_EPS 1e-5f

// ---------------- degree histogram ----------------
__global__ void count_kernel(const int* __restrict__ ei, int E, int* __restrict__ cnt) {
    int i = blockIdx.x * blockDim.x + threadIdx.x;
    if (i < E) atomicAdd(&cnt[ei[E + i]], 1);   // dst = ei[1][i]
}

// ---------------- exclusive scan over N counts (single block) ----------------
__global__ __launch_bounds__(1024) void scan_kernel(const int* __restrict__ cnt,
                                                    int* __restrict__ row_start, int n) {
    __shared__ int part[1024];
    int t = threadIdx.x;
    int chunk = (n + 1023) >> 10;
    int lo = t * chunk;
    int hi = lo + chunk; if (hi > n) hi = n;
    int s = 0;
    for (int i = lo; i < hi; ++i) s += cnt[i];
    part[t] = s;
    __syncthreads();
    // Hillis-Steele inclusive scan
    for (int off = 1; off < 1024; off <<= 1) {
        int add = (t >= off) ? part[t - off] : 0;
        __syncthreads();
        part[t] += add;
        __syncthreads();
    }
    int run = (t == 0) ? 0 : part[t - 1];
    for (int i = lo; i < hi; ++i) { row_start[i] = run; run += cnt[i]; }
    if (t == 1023) row_start[n] = part[1023];
}

// ---------------- CSR fill (store src per slot) ----------------
__global__ void fill_kernel(const int* __restrict__ ei, int E,
                            const int* __restrict__ row_start,
                            int* __restrict__ cursor, int* __restrict__ colidx) {
    int i = blockIdx.x * blockDim.x + threadIdx.x;
    if (i < E) {
        int d = ei[E + i];
        int p = atomicAdd(&cursor[d], 1);
        colidx[row_start[d] + p] = ei[i];   // src
    }
}

// ---------------- fp32 tiled GEMM: C[M x (2*NH)] = A[M x K] @ [Bl | Br] ----------------
// 128x128 block tile, 256 threads, 8x8 per thread, BK=16.
__global__ __launch_bounds__(256) void gemm128(
    const float* __restrict__ A, long lda, int M, int K,
    const float* __restrict__ Bl, const float* __restrict__ Br, int ldb, int NH,
    float* __restrict__ C, int ldc)
{
    __shared__ float As[16][132];   // transposed: As[k][row]
    __shared__ float Bs[16][132];   // Bs[k][col]
    const int t = threadIdx.x;
    const int row0 = blockIdx.x * 128;
    const int col0 = blockIdx.y * 128;

    // A tile load map: 128 rows x 16 k, 8 floats/thread
    const int a_row = t >> 1;
    const int a_k   = (t & 1) * 8;
    int ga_row = row0 + a_row; if (ga_row >= M) ga_row = M - 1;
    const float* Ap = A + (long)ga_row * lda + a_k;

    // B tile load map: 16 k x 128 cols, 8 floats/thread
    const int b_row = t >> 4;
    const int b_col = (t & 15) * 8;
    const int gcol = col0 + b_col;
    const float* Bp = (gcol < NH) ? (Bl + (long)b_row * ldb + gcol)
                                  : (Br + (long)b_row * ldb + (gcol - NH));

    const int tx = t & 15, ty = t >> 4;
    float acc[8][8];
#pragma unroll
    for (int i = 0; i < 8; ++i)
#pragma unroll
        for (int j = 0; j < 8; ++j) acc[i][j] = 0.f;

    for (int k0 = 0; k0 < K; k0 += 16) {
        float4 a0 = *(const float4*)(Ap + k0);
        float4 a1 = *(const float4*)(Ap + k0 + 4);
        float4 b0 = *(const float4*)(Bp + (long)k0 * ldb);
        float4 b1 = *(const float4*)(Bp + (long)k0 * ldb + 4);
        As[a_k + 0][a_row] = a0.x; As[a_k + 1][a_row] = a0.y;
        As[a_k + 2][a_row] = a0.z; As[a_k + 3][a_row] = a0.w;
        As[a_k + 4][a_row] = a1.x; As[a_k + 5][a_row] = a1.y;
        As[a_k + 6][a_row] = a1.z; As[a_k + 7][a_row] = a1.w;
        *(float4*)&Bs[b_row][b_col]     = b0;
        *(float4*)&Bs[b_row][b_col + 4] = b1;
        __syncthreads();
#pragma unroll
        for (int kk = 0; kk < 16; ++kk) {
            float a[8], b[8];
            *(float4*)&a[0] = *(const float4*)&As[kk][ty * 8];
            *(float4*)&a[4] = *(const float4*)&As[kk][ty * 8 + 4];
            *(float4*)&b[0] = *(const float4*)&Bs[kk][tx * 8];
            *(float4*)&b[4] = *(const float4*)&Bs[kk][tx * 8 + 4];
#pragma unroll
            for (int i = 0; i < 8; ++i)
#pragma unroll
                for (int j = 0; j < 8; ++j)
                    acc[i][j] = fmaf(a[i], b[j], acc[i][j]);
        }
        __syncthreads();
    }
#pragma unroll
    for (int i = 0; i < 8; ++i) {
        int r = row0 + ty * 8 + i;
        if (r < M) {
            float* Cp = C + (long)r * ldc + col0 + tx * 8;
            float4 v0 = make_float4(acc[i][0], acc[i][1], acc[i][2], acc[i][3]);
            float4 v1 = make_float4(acc[i][4], acc[i][5], acc[i][6], acc[i][7]);
            *(float4*)Cp       = v0;
            *(float4*)(Cp + 4) = v1;
        }
    }
}

// ---------------- layer-1 aggregation + bias + BN + ReLU (one wave per dst node) ----
// Y layout: [N][1024]: cols 0..511 = x@W1l, cols 512..1023 = x@W1r (overwritten by h)
__global__ __launch_bounds__(256) void agg1_kernel(
    float* __restrict__ Y,
    const int* __restrict__ row_start, const int* __restrict__ colidx,
    const float* __restrict__ b1, const float* __restrict__ gamma,
    const float* __restrict__ beta, const float* __restrict__ mean,
    const float* __restrict__ var, int n)
{
    int wid  = (blockIdx.x * blockDim.x + threadIdx.x) >> 6;
    int lane = threadIdx.x & 63;
    if (wid >= n) return;
    int s0 = row_start[wid], s1 = row_start[wid + 1];
    int c0 = lane * 8;
    float acc[8] = {0, 0, 0, 0, 0, 0, 0, 0};
    for (int i = s0; i < s1; ++i) {
        int src = colidx[i];
        const float* r = Y + (size_t)src * 1024 + c0;
        float4 v0 = *(const float4*)r;
        float4 v1 = *(const float4*)(r + 4);
        acc[0] += v0.x; acc[1] += v0.y; acc[2] += v0.z; acc[3] += v0.w;
        acc[4] += v1.x; acc[5] += v1.y; acc[6] += v1.z; acc[7] += v1.w;
    }
    float inv = 1.0f / fmaxf((float)(s1 - s0), 1.0f);
    float* yr = Y + (size_t)wid * 1024 + 512 + c0;
    float yrv[8];
    *(float4*)&yrv[0] = *(const float4*)yr;
    *(float4*)&yrv[4] = *(const float4*)(yr + 4);
    float outv[8];
#pragma unroll
    for (int j = 0; j < 8; ++j) {
        int c = c0 + j;
        float sc = gamma[c] * rsqrtf(var[c] + BN_EPS);
        float sh = beta[c] - mean[c] * sc;
        float pre = acc[j] * inv + b1[c] + yrv[j];
        float h = pre * sc + sh;
        outv[j] = fmaxf(h, 0.0f);
    }
    *(float4*)yr       = *(float4*)&outv[0];
    *(float4*)(yr + 4) = *(float4*)&outv[4];
}

// ---------------- layer-2 aggregation + bias + write output ----------------
// U layout: [N][128]: cols 0..63 = h@W2l, cols 64..127 = h@W2r
__global__ __launch_bounds__(256) void agg2_kernel(
    const float* __restrict__ U,
    const int* __restrict__ row_start, const int* __restrict__ colidx,
    const float* __restrict__ b2, float* __restrict__ out, int n)
{
    int wid  = (blockIdx.x * blockDim.x + threadIdx.x) >> 6;
    int lane = threadIdx.x & 63;
    if (wid >= n) return;
    int s0 = row_start[wid], s1 = row_start[wid + 1];
    float acc = 0.f;
    for (int i = s0; i < s1; ++i) {
        int src = colidx[i];
        acc += U[(size_t)src * 128 + lane];
    }
    float inv = 1.0f / fmaxf((float)(s1 - s0), 1.0f);
    float z = acc * inv + b2[lane] + U[(size_t)wid * 128 + 64 + lane];
    out[(size_t)wid * 64 + lane] = z;
}

extern "C" void kernel_launch(void* const* d_in, const int* in_sizes, int n_in,
                              void* d_out, int out_size, void* d_ws, size_t ws_size,
                              hipStream_t stream) {
    const float* x     = (const float*)d_in[0];
    const int*   ei    = (const int*)d_in[1];
    const float* W1l   = (const float*)d_in[2];
    const float* b1    = (const float*)d_in[3];
    const float* W1r   = (const float*)d_in[4];
    const float* gamma = (const float*)d_in[5];
    const float* beta  = (const float*)d_in[6];
    const float* mean  = (const float*)d_in[7];
    const float* var   = (const float*)d_in[8];
    const float* W2l   = (const float*)d_in[9];
    const float* b2    = (const float*)d_in[10];
    const float* W2r   = (const float*)d_in[11];
    float* out = (float*)d_out;

    const int N = in_sizes[0] / 2000;   // 50000
    const int E = in_sizes[1] / 2;      // 800000

    // Workspace layout
    char* ws = (char*)d_ws;
    float* Y = (float*)ws;                                    // N*1024 f32
    float* U = (float*)(ws + (size_t)N * 1024 * 4);           // N*128 f32
    int* cnt       = (int*)(ws + (size_t)N * 1024 * 4 + (size_t)N * 128 * 4);
    int* row_start = cnt + N;          // N+1
    int* cursor    = row_start + N + 4;
    int* colidx    = cursor + N;       // E

    hipMemsetAsync(cnt, 0, (size_t)N * sizeof(int), stream);
    hipMemsetAsync(cursor, 0, (size_t)N * sizeof(int), stream);

    int eb = (E + 255) / 256;
    count_kernel<<<eb, 256, 0, stream>>>(ei, E, cnt);
    scan_kernel<<<1, 1024, 0, stream>>>(cnt, row_start, N);
    fill_kernel<<<eb, 256, 0, stream>>>(ei, E, row_start, cursor, colidx);

    // GEMM1: Y = x @ [W1l | W1r]   (M=N, K=2000, out cols=1024)
    gemm128<<<dim3((N + 127) / 128, 8), 256, 0, stream>>>(
        x, 2000, N, 2000, W1l, W1r, 512, 512, Y, 1024);

    // agg + b1 + BN + ReLU -> h stored in Y[:,512:1024]
    agg1_kernel<<<(N + 3) / 4, 256, 0, stream>>>(
        Y, row_start, colidx, b1, gamma, beta, mean, var, N);

    // GEMM2: U = h @ [W2l | W2r]   (M=N, K=512, out cols=128)
    gemm128<<<dim3((N + 127) / 128, 1), 256, 0, stream>>>(
        Y + 512, 1024, N, 512, W2l, W2r, 64, 64, U, 128);

    // agg + b2 + u_r -> out
    agg2_kernel<<<(N + 3) / 4, 256, 0, stream>>>(
        U, row_start, colidx, b2, out, N);
}

// Round 2
// 1156.073 us; speedup vs baseline: 2.6465x; 2.6465x over previous
//
#include <hip/hip_runtime.h>

// GraphSAGE encoder, restructured: aggregate AFTER linear maps.
//   N=50000, G=2000, E=800000, H=512, Z=64
// GEMM1 (x @ [W1l|W1r], 2.05e11 FLOP) now bf16 MFMA; everything else fp32.

#define BN_EPS 1e-5f
#define GK 2000      // K of GEMM1
#define KP 2048      // padded K for BT
#define NT 63        // ceil(2000/32) K-steps of 32

typedef __attribute__((ext_vector_type(8))) short bf16x8;
typedef __attribute__((ext_vector_type(4))) float f32x4;
typedef unsigned short u16x8 __attribute__((ext_vector_type(8)));

__device__ inline unsigned short f2bf(float f) {
    union { float f; unsigned u; } v; v.f = f;
    unsigned r = (v.u + 0x7fffu + ((v.u >> 16) & 1u)) >> 16;
    return (unsigned short)r;
}

#define GLL16(gp, lp) __builtin_amdgcn_global_load_lds( \
    (const __attribute__((address_space(1))) void*)(gp), \
    (__attribute__((address_space(3))) void*)(lp), 16, 0, 0)

// ---------------- degree histogram ----------------
__global__ void count_kernel(const int* __restrict__ ei, int E, int* __restrict__ cnt) {
    int i = blockIdx.x * blockDim.x + threadIdx.x;
    if (i < E) atomicAdd(&cnt[ei[E + i]], 1);   // dst = ei[1][i]
}

// ---------------- exclusive scan over N counts (single block) ----------------
__global__ __launch_bounds__(1024) void scan_kernel(const int* __restrict__ cnt,
                                                    int* __restrict__ row_start, int n) {
    __shared__ int part[1024];
    int t = threadIdx.x;
    int chunk = (n + 1023) >> 10;
    int lo = t * chunk;
    int hi = lo + chunk; if (hi > n) hi = n;
    int s = 0;
    for (int i = lo; i < hi; ++i) s += cnt[i];
    part[t] = s;
    __syncthreads();
    for (int off = 1; off < 1024; off <<= 1) {
        int add = (t >= off) ? part[t - off] : 0;
        __syncthreads();
        part[t] += add;
        __syncthreads();
    }
    int run = (t == 0) ? 0 : part[t - 1];
    for (int i = lo; i < hi; ++i) { row_start[i] = run; run += cnt[i]; }
    if (t == 1023) row_start[n] = part[1023];
}

// ---------------- CSR fill ----------------
__global__ void fill_kernel(const int* __restrict__ ei, int E,
                            const int* __restrict__ row_start,
                            int* __restrict__ cursor, int* __restrict__ colidx) {
    int i = blockIdx.x * blockDim.x + threadIdx.x;
    if (i < E) {
        int d = ei[E + i];
        int p = atomicAdd(&cursor[d], 1);
        colidx[row_start[d] + p] = ei[i];   // src
    }
}

// ---------------- build BT[1024][2048] bf16 = [W1l|W1r]^T, zero-padded ----------------
__global__ __launch_bounds__(256) void prep_bt(const float* __restrict__ W1l,
                                               const float* __restrict__ W1r,
                                               unsigned short* __restrict__ BT) {
    int idx = blockIdx.x * 256 + threadIdx.x;   // 1024 cols * 256 groups-of-8
    int c  = idx >> 8;
    int k0 = (idx & 255) << 3;
    const float* W = (c < 512) ? (W1l + c) : (W1r + (c - 512));
    unsigned short us[8];
#pragma unroll
    for (int j = 0; j < 8; ++j) {
        int k = k0 + j;
        float v = (k < GK) ? W[(size_t)k * 512] : 0.0f;
        us[j] = f2bf(v);
    }
    *(u16x8*)&BT[(size_t)c * KP + k0] = *(u16x8*)us;
}

// ---------------- GEMM1: C[M x 1024] = A[M x 2000](f32) @ BT^T (bf16 MFMA) ----------
// 128x128 tile, 256 threads (4 waves as 2x2 of 64x64), BK=32, 16x16x32 MFMA.
// A reg-staged + converted to bf16 in-kernel; B staged via global_load_lds (dbuf).
__global__ __launch_bounds__(256) void gemm1_bf16(
    const float* __restrict__ A, int M,
    const unsigned short* __restrict__ BT,
    float* __restrict__ C)
{
    __shared__ __align__(16) unsigned short As[128][32];
    __shared__ __align__(16) unsigned short Bs[2][128][32];

    const int t    = threadIdx.x;
    const int wid  = t >> 6;
    const int lane = t & 63;
    const int row0 = blockIdx.y * 128;
    const int col0 = blockIdx.x * 128;

    // A staging map: thread t -> tile row ar, k-offset akq (0 or 16), 16 floats
    const int ar  = t >> 1;
    const int akq = (t & 1) << 4;
    int garow = row0 + ar; if (garow >= M) garow = M - 1;
    const float* aptr = A + (size_t)garow * GK + akq;

    // B staging map for global_load_lds: chunk i = j*256 + wid*64 + lane
    const int i0 = wid * 64 + lane;
    const unsigned short* bptr0 = BT + ((size_t)(col0 + (i0 >> 2)) * KP + ((i0 & 3) << 3));
    const unsigned short* bptr1 = bptr0 + (size_t)64 * KP;

    // fragment read map
    const int wr   = wid >> 1, wc = wid & 1;
    const int fr16 = lane & 15;
    const int kb8  = (lane >> 4) << 3;

    f32x4 acc[4][4];
#pragma unroll
    for (int m = 0; m < 4; ++m)
#pragma unroll
        for (int n = 0; n < 4; ++n) acc[m][n] = (f32x4)0.0f;

    // prologue: stage B tile 0 into buf 0; load A tile 0 into regs
    GLL16(bptr0, &Bs[0][wid * 16][0]);
    GLL16(bptr1, &Bs[0][64 + wid * 16][0]);

    float fr[16];
    {
        const float4* p = (const float4*)aptr;
        float4 v0 = p[0], v1 = p[1], v2 = p[2], v3 = p[3];
        fr[0]=v0.x; fr[1]=v0.y; fr[2]=v0.z;  fr[3]=v0.w;
        fr[4]=v1.x; fr[5]=v1.y; fr[6]=v1.z;  fr[7]=v1.w;
        fr[8]=v2.x; fr[9]=v2.y; fr[10]=v2.z; fr[11]=v2.w;
        fr[12]=v3.x;fr[13]=v3.y;fr[14]=v3.z; fr[15]=v3.w;
    }

    int cur = 0;
    for (int it = 0; it < NT; ++it) {
        // convert + ds_write A tile 'it'
        {
            unsigned short us[16];
#pragma unroll
            for (int j = 0; j < 16; ++j) us[j] = f2bf(fr[j]);
            *(u16x8*)&As[ar][akq]     = *(u16x8*)&us[0];
            *(u16x8*)&As[ar][akq + 8] = *(u16x8*)&us[8];
        }
        __syncthreads();   // A writes visible; B(it) vmcnt drained

        if (it + 1 < NT) {
            // prefetch A regs for tile it+1 (latency hides under MFMA below)
            int kb = (it + 1) * 32 + akq;
            if (kb < GK) {
                const float4* p = (const float4*)(aptr + (size_t)(it + 1) * 32);
                float4 v0 = p[0], v1 = p[1], v2 = p[2], v3 = p[3];
                fr[0]=v0.x; fr[1]=v0.y; fr[2]=v0.z;  fr[3]=v0.w;
                fr[4]=v1.x; fr[5]=v1.y; fr[6]=v1.z;  fr[7]=v1.w;
                fr[8]=v2.x; fr[9]=v2.y; fr[10]=v2.z; fr[11]=v2.w;
                fr[12]=v3.x;fr[13]=v3.y;fr[14]=v3.z; fr[15]=v3.w;
            } else {
#pragma unroll
                for (int j = 0; j < 16; ++j) fr[j] = 0.0f;
            }
            // stage B tile it+1 into the other buffer
            const unsigned short* bp = bptr0 + (size_t)(it + 1) * 32;
            GLL16(bp,                   &Bs[cur ^ 1][wid * 16][0]);
            GLL16(bp + (size_t)64 * KP, &Bs[cur ^ 1][64 + wid * 16][0]);
        }

        // fragments + MFMA
        bf16x8 af[4], bfr[4];
#pragma unroll
        for (int m = 0; m < 4; ++m)
            af[m] = *(const bf16x8*)&As[wr * 64 + m * 16 + fr16][kb8];
#pragma unroll
        for (int n = 0; n < 4; ++n)
            bfr[n] = *(const bf16x8*)&Bs[cur][wc * 64 + n * 16 + fr16][kb8];
#pragma unroll
        for (int m = 0; m < 4; ++m)
#pragma unroll
            for (int n = 0; n < 4; ++n)
                acc[m][n] = __builtin_amdgcn_mfma_f32_16x16x32_bf16(
                    af[m], bfr[n], acc[m][n], 0, 0, 0);

        __syncthreads();   // As/Bs[cur^1] safe to rewrite/read next iter
        cur ^= 1;
    }

    // epilogue: C write (row = (lane>>4)*4 + r, col = lane&15 within fragment)
    const int crow = (lane >> 4) << 2;
#pragma unroll
    for (int m = 0; m < 4; ++m) {
        int rbase = row0 + wr * 64 + m * 16 + crow;
#pragma unroll
        for (int r = 0; r < 4; ++r) {
            int row = rbase + r;
            if (row < M) {
                float* Cp = C + (size_t)row * 1024 + col0 + wc * 64 + fr16;
#pragma unroll
                for (int n = 0; n < 4; ++n)
                    Cp[n * 16] = acc[m][n][r];
            }
        }
    }
}

// ---------------- fp32 tiled GEMM (kept for layer 2) ----------------
__global__ __launch_bounds__(256) void gemm128(
    const float* __restrict__ A, long lda, int M, int K,
    const float* __restrict__ Bl, const float* __restrict__ Br, int ldb, int NH,
    float* __restrict__ C, int ldc)
{
    __shared__ float As[16][132];
    __shared__ float Bs[16][132];
    const int t = threadIdx.x;
    const int row0 = blockIdx.x * 128;
    const int col0 = blockIdx.y * 128;

    const int a_row = t >> 1;
    const int a_k   = (t & 1) * 8;
    int ga_row = row0 + a_row; if (ga_row >= M) ga_row = M - 1;
    const float* Ap = A + (long)ga_row * lda + a_k;

    const int b_row = t >> 4;
    const int b_col = (t & 15) * 8;
    const int gcol = col0 + b_col;
    const float* Bp = (gcol < NH) ? (Bl + (long)b_row * ldb + gcol)
                                  : (Br + (long)b_row * ldb + (gcol - NH));

    const int tx = t & 15, ty = t >> 4;
    float acc[8][8];
#pragma unroll
    for (int i = 0; i < 8; ++i)
#pragma unroll
        for (int j = 0; j < 8; ++j) acc[i][j] = 0.f;

    for (int k0 = 0; k0 < K; k0 += 16) {
        float4 a0 = *(const float4*)(Ap + k0);
        float4 a1 = *(const float4*)(Ap + k0 + 4);
        float4 b0 = *(const float4*)(Bp + (long)k0 * ldb);
        float4 b1 = *(const float4*)(Bp + (long)k0 * ldb + 4);
        As[a_k + 0][a_row] = a0.x; As[a_k + 1][a_row] = a0.y;
        As[a_k + 2][a_row] = a0.z; As[a_k + 3][a_row] = a0.w;
        As[a_k + 4][a_row] = a1.x; As[a_k + 5][a_row] = a1.y;
        As[a_k + 6][a_row] = a1.z; As[a_k + 7][a_row] = a1.w;
        *(float4*)&Bs[b_row][b_col]     = b0;
        *(float4*)&Bs[b_row][b_col + 4] = b1;
        __syncthreads();
#pragma unroll
        for (int kk = 0; kk < 16; ++kk) {
            float a[8], b[8];
            *(float4*)&a[0] = *(const float4*)&As[kk][ty * 8];
            *(float4*)&a[4] = *(const float4*)&As[kk][ty * 8 + 4];
            *(float4*)&b[0] = *(const float4*)&Bs[kk][tx * 8];
            *(float4*)&b[4] = *(const float4*)&Bs[kk][tx * 8 + 4];
#pragma unroll
            for (int i = 0; i < 8; ++i)
#pragma unroll
                for (int j = 0; j < 8; ++j)
                    acc[i][j] = fmaf(a[i], b[j], acc[i][j]);
        }
        __syncthreads();
    }
#pragma unroll
    for (int i = 0; i < 8; ++i) {
        int r = row0 + ty * 8 + i;
        if (r < M) {
            float* Cp = C + (long)r * ldc + col0 + tx * 8;
            float4 v0 = make_float4(acc[i][0], acc[i][1], acc[i][2], acc[i][3]);
            float4 v1 = make_float4(acc[i][4], acc[i][5], acc[i][6], acc[i][7]);
            *(float4*)Cp       = v0;
            *(float4*)(Cp + 4) = v1;
        }
    }
}

// ---------------- layer-1 aggregation + bias + BN + ReLU ----------------
__global__ __launch_bounds__(256) void agg1_kernel(
    float* __restrict__ Y,
    const int* __restrict__ row_start, const int* __restrict__ colidx,
    const float* __restrict__ b1, const float* __restrict__ gamma,
    const float* __restrict__ beta, const float* __restrict__ mean,
    const float* __restrict__ var, int n)
{
    int wid  = (blockIdx.x * blockDim.x + threadIdx.x) >> 6;
    int lane = threadIdx.x & 63;
    if (wid >= n) return;
    int s0 = row_start[wid], s1 = row_start[wid + 1];
    int c0 = lane * 8;
    float acc[8] = {0, 0, 0, 0, 0, 0, 0, 0};
    for (int i = s0; i < s1; ++i) {
        int src = colidx[i];
        const float* r = Y + (size_t)src * 1024 + c0;
        float4 v0 = *(const float4*)r;
        float4 v1 = *(const float4*)(r + 4);
        acc[0] += v0.x; acc[1] += v0.y; acc[2] += v0.z; acc[3] += v0.w;
        acc[4] += v1.x; acc[5] += v1.y; acc[6] += v1.z; acc[7] += v1.w;
    }
    float inv = 1.0f / fmaxf((float)(s1 - s0), 1.0f);
    float* yr = Y + (size_t)wid * 1024 + 512 + c0;
    float yrv[8];
    *(float4*)&yrv[0] = *(const float4*)yr;
    *(float4*)&yrv[4] = *(const float4*)(yr + 4);
    float outv[8];
#pragma unroll
    for (int j = 0; j < 8; ++j) {
        int c = c0 + j;
        float sc = gamma[c] * rsqrtf(var[c] + BN_EPS);
        float sh = beta[c] - mean[c] * sc;
        float pre = acc[j] * inv + b1[c] + yrv[j];
        float h = pre * sc + sh;
        outv[j] = fmaxf(h, 0.0f);
    }
    *(float4*)yr       = *(float4*)&outv[0];
    *(float4*)(yr + 4) = *(float4*)&outv[4];
}

// ---------------- layer-2 aggregation + bias + output ----------------
__global__ __launch_bounds__(256) void agg2_kernel(
    const float* __restrict__ U,
    const int* __restrict__ row_start, const int* __restrict__ colidx,
    const float* __restrict__ b2, float* __restrict__ out, int n)
{
    int wid  = (blockIdx.x * blockDim.x + threadIdx.x) >> 6;
    int lane = threadIdx.x & 63;
    if (wid >= n) return;
    int s0 = row_start[wid], s1 = row_start[wid + 1];
    float acc = 0.f;
    for (int i = s0; i < s1; ++i) {
        int src = colidx[i];
        acc += U[(size_t)src * 128 + lane];
    }
    float inv = 1.0f / fmaxf((float)(s1 - s0), 1.0f);
    float z = acc * inv + b2[lane] + U[(size_t)wid * 128 + 64 + lane];
    out[(size_t)wid * 64 + lane] = z;
}

extern "C" void kernel_launch(void* const* d_in, const int* in_sizes, int n_in,
                              void* d_out, int out_size, void* d_ws, size_t ws_size,
                              hipStream_t stream) {
    const float* x     = (const float*)d_in[0];
    const int*   ei    = (const int*)d_in[1];
    const float* W1l   = (const float*)d_in[2];
    const float* b1    = (const float*)d_in[3];
    const float* W1r   = (const float*)d_in[4];
    const float* gamma = (const float*)d_in[5];
    const float* beta  = (const float*)d_in[6];
    const float* mean  = (const float*)d_in[7];
    const float* var   = (const float*)d_in[8];
    const float* W2l   = (const float*)d_in[9];
    const float* b2    = (const float*)d_in[10];
    const float* W2r   = (const float*)d_in[11];
    float* out = (float*)d_out;

    const int N = in_sizes[0] / 2000;   // 50000
    const int E = in_sizes[1] / 2;      // 800000

    // Workspace layout (same 234 MB footprint as round 1):
    //   Y [N*1024 f32] | U [N*128 f32] (BT bf16 [1024*2048] aliases U's first 4.2MB,
    //   dead before GEMM2 writes U) | cnt | row_start | cursor | colidx
    char* ws = (char*)d_ws;
    float* Y = (float*)ws;
    float* U = (float*)(ws + (size_t)N * 1024 * 4);
    unsigned short* BT = (unsigned short*)U;
    int* cnt       = (int*)(ws + (size_t)N * 1024 * 4 + (size_t)N * 128 * 4);
    int* row_start = cnt + N;
    int* cursor    = row_start + N + 4;
    int* colidx    = cursor + N;

    hipMemsetAsync(cnt, 0, (size_t)N * sizeof(int), stream);
    hipMemsetAsync(cursor, 0, (size_t)N * sizeof(int), stream);

    // weights -> transposed padded bf16
    prep_bt<<<1024, 256, 0, stream>>>(W1l, W1r, BT);

    int eb = (E + 255) / 256;
    count_kernel<<<eb, 256, 0, stream>>>(ei, E, cnt);
    scan_kernel<<<1, 1024, 0, stream>>>(cnt, row_start, N);
    fill_kernel<<<eb, 256, 0, stream>>>(ei, E, row_start, cursor, colidx);

    // GEMM1 (bf16 MFMA): Y = x @ [W1l | W1r]; col-blocks fastest for A-panel reuse
    gemm1_bf16<<<dim3(8, (N + 127) / 128), 256, 0, stream>>>(x, N, BT, Y);

    // agg + b1 + BN + ReLU -> h in Y[:,512:1024]
    agg1_kernel<<<(N + 3) / 4, 256, 0, stream>>>(
        Y, row_start, colidx, b1, gamma, beta, mean, var, N);

    // GEMM2 (fp32): U = h @ [W2l | W2r]
    gemm128<<<dim3((N + 127) / 128, 1), 256, 0, stream>>>(
        Y + 512, 1024, N, 512, W2l, W2r, 64, 64, U, 128);

    // agg + b2 + u_r -> out
    agg2_kernel<<<(N + 3) / 4, 256, 0, stream>>>(
        U, row_start, colidx, b2, out, N);
}

// Round 3
// 858.008 us; speedup vs baseline: 3.5658x; 1.3474x over previous
//
#include <hip/hip_runtime.h>

// GraphSAGE encoder, restructured: aggregate AFTER linear maps.
//   N=50000, G=2000, E=800000, H=512, Z=64
// GEMM1: bf16 MFMA, XCD-swizzled grid, bf16 output.
// agg1 / GEMM2 / agg2: all-bf16 intermediate dataflow, fp32 accumulation.

#define BN_EPS 1e-5f
#define GK 2000      // K of GEMM1
#define KP 2048      // padded K for BT
#define NT1 63       // ceil(2000/32)
#define NT2 16       // 512/32

typedef __attribute__((ext_vector_type(8))) short bf16x8;
typedef __attribute__((ext_vector_type(4))) float f32x4;
typedef unsigned short u16x8 __attribute__((ext_vector_type(8)));

__device__ inline unsigned short f2bf(float f) {
    union { float f; unsigned u; } v; v.f = f;
    unsigned r = (v.u + 0x7fffu + ((v.u >> 16) & 1u)) >> 16;
    return (unsigned short)r;
}
__device__ inline float bf2f(unsigned short u) {
    union { unsigned u; float f; } v; v.u = ((unsigned)u) << 16;
    return v.f;
}

#define GLL16(gp, lp) __builtin_amdgcn_global_load_lds( \
    (const __attribute__((address_space(1))) void*)(gp), \
    (__attribute__((address_space(3))) void*)(lp), 16, 0, 0)

// ---------------- degree histogram ----------------
__global__ void count_kernel(const int* __restrict__ ei, int E, int* __restrict__ cnt) {
    int i = blockIdx.x * blockDim.x + threadIdx.x;
    if (i < E) atomicAdd(&cnt[ei[E + i]], 1);   // dst = ei[1][i]
}

// ---------------- exclusive scan over N counts (single block) ----------------
__global__ __launch_bounds__(1024) void scan_kernel(const int* __restrict__ cnt,
                                                    int* __restrict__ row_start, int n) {
    __shared__ int part[1024];
    int t = threadIdx.x;
    int chunk = (n + 1023) >> 10;
    int lo = t * chunk;
    int hi = lo + chunk; if (hi > n) hi = n;
    int s = 0;
    for (int i = lo; i < hi; ++i) s += cnt[i];
    part[t] = s;
    __syncthreads();
    for (int off = 1; off < 1024; off <<= 1) {
        int add = (t >= off) ? part[t - off] : 0;
        __syncthreads();
        part[t] += add;
        __syncthreads();
    }
    int run = (t == 0) ? 0 : part[t - 1];
    for (int i = lo; i < hi; ++i) { row_start[i] = run; run += cnt[i]; }
    if (t == 1023) row_start[n] = part[1023];
}

// ---------------- CSR fill ----------------
__global__ void fill_kernel(const int* __restrict__ ei, int E,
                            const int* __restrict__ row_start,
                            int* __restrict__ cursor, int* __restrict__ colidx) {
    int i = blockIdx.x * blockDim.x + threadIdx.x;
    if (i < E) {
        int d = ei[E + i];
        int p = atomicAdd(&cursor[d], 1);
        colidx[row_start[d] + p] = ei[i];   // src
    }
}

// ---------------- BT1[1024][2048] bf16 = [W1l|W1r]^T, zero-padded ----------------
__global__ __launch_bounds__(256) void prep_bt(const float* __restrict__ W1l,
                                               const float* __restrict__ W1r,
                                               unsigned short* __restrict__ BT) {
    int idx = blockIdx.x * 256 + threadIdx.x;   // 1024 cols * 256 groups-of-8
    int c  = idx >> 8;
    int k0 = (idx & 255) << 3;
    const float* W = (c < 512) ? (W1l + c) : (W1r + (c - 512));
    unsigned short us[8];
#pragma unroll
    for (int j = 0; j < 8; ++j) {
        int k = k0 + j;
        float v = (k < GK) ? W[(size_t)k * 512] : 0.0f;
        us[j] = f2bf(v);
    }
    *(u16x8*)&BT[(size_t)c * KP + k0] = *(u16x8*)us;
}

// ---------------- BT2[128][512] bf16 = [W2l|W2r]^T ----------------
__global__ __launch_bounds__(256) void prep_bt2(const float* __restrict__ W2l,
                                                const float* __restrict__ W2r,
                                                unsigned short* __restrict__ BT2) {
    int idx = blockIdx.x * 256 + threadIdx.x;   // 128 cols * 64 groups-of-8 = 8192
    int c  = idx >> 6;
    int k0 = (idx & 63) << 3;
    const float* W = (c < 64) ? (W2l + c) : (W2r + (c - 64));
    unsigned short us[8];
#pragma unroll
    for (int j = 0; j < 8; ++j) us[j] = f2bf(W[(size_t)(k0 + j) * 64]);
    *(u16x8*)&BT2[(size_t)c * 512 + k0] = *(u16x8*)us;
}

// ---------------- GEMM1: Y[M x 1024](bf16) = A[M x 2000](f32) @ BT1^T ------------
// 128x128 tile, 4 waves (2x2 of 64x64), BK=32, 16x16x32 MFMA, XCD-swizzled 1D grid.
__global__ __launch_bounds__(256) void gemm1_bf16(
    const float* __restrict__ A, int M,
    const unsigned short* __restrict__ BT,
    unsigned short* __restrict__ Y)
{
    __shared__ __align__(16) unsigned short As[128][32];
    __shared__ __align__(16) unsigned short Bs[2][128][32];

    const int t    = threadIdx.x;
    const int wid  = t >> 6;
    const int lane = t & 63;

    // XCD-bijective swizzle: nwg = 8*nby (nwg%8==0). Each XCD gets contiguous
    // row-panels with all 8 col-blocks -> A panel fetched ~once per HBM.
    const int nby = (M + 127) >> 7;
    const int b   = blockIdx.x;
    const int swz = (b & 7) * nby + (b >> 3);
    const int row0 = (swz >> 3) << 7;
    const int col0 = (swz & 7) << 7;

    // A staging map: thread t -> tile row ar, k-offset akq (0 or 16), 16 floats
    const int ar  = t >> 1;
    const int akq = (t & 1) << 4;
    int garow = row0 + ar; if (garow >= M) garow = M - 1;
    const float* aptr = A + (size_t)garow * GK + akq;

    // B staging map: chunk i0 = wid*64+lane (x2 calls)
    const int i0 = wid * 64 + lane;
    const unsigned short* bptr0 = BT + ((size_t)(col0 + (i0 >> 2)) * KP + ((i0 & 3) << 3));
    const unsigned short* bptr1 = bptr0 + (size_t)64 * KP;

    const int wr   = wid >> 1, wc = wid & 1;
    const int fr16 = lane & 15;
    const int kb8  = (lane >> 4) << 3;

    f32x4 acc[4][4];
#pragma unroll
    for (int m = 0; m < 4; ++m)
#pragma unroll
        for (int n = 0; n < 4; ++n) acc[m][n] = (f32x4)0.0f;

    // prologue
    GLL16(bptr0, &Bs[0][wid * 16][0]);
    GLL16(bptr1, &Bs[0][64 + wid * 16][0]);

    float fr[16];
    {
        const float4* p = (const float4*)aptr;
        float4 v0 = p[0], v1 = p[1], v2 = p[2], v3 = p[3];
        fr[0]=v0.x; fr[1]=v0.y; fr[2]=v0.z;  fr[3]=v0.w;
        fr[4]=v1.x; fr[5]=v1.y; fr[6]=v1.z;  fr[7]=v1.w;
        fr[8]=v2.x; fr[9]=v2.y; fr[10]=v2.z; fr[11]=v2.w;
        fr[12]=v3.x;fr[13]=v3.y;fr[14]=v3.z; fr[15]=v3.w;
    }

    int cur = 0;
    for (int it = 0; it < NT1; ++it) {
        {
            unsigned short us[16];
#pragma unroll
            for (int j = 0; j < 16; ++j) us[j] = f2bf(fr[j]);
            *(u16x8*)&As[ar][akq]     = *(u16x8*)&us[0];
            *(u16x8*)&As[ar][akq + 8] = *(u16x8*)&us[8];
        }
        __syncthreads();   // A writes visible; B(it) vmcnt drained

        if (it + 1 < NT1) {
            int kb = (it + 1) * 32 + akq;
            if (kb < GK) {
                const float4* p = (const float4*)(aptr + (size_t)(it + 1) * 32);
                float4 v0 = p[0], v1 = p[1], v2 = p[2], v3 = p[3];
                fr[0]=v0.x; fr[1]=v0.y; fr[2]=v0.z;  fr[3]=v0.w;
                fr[4]=v1.x; fr[5]=v1.y; fr[6]=v1.z;  fr[7]=v1.w;
                fr[8]=v2.x; fr[9]=v2.y; fr[10]=v2.z; fr[11]=v2.w;
                fr[12]=v3.x;fr[13]=v3.y;fr[14]=v3.z; fr[15]=v3.w;
            } else {
#pragma unroll
                for (int j = 0; j < 16; ++j) fr[j] = 0.0f;
            }
            const unsigned short* bp = bptr0 + (size_t)(it + 1) * 32;
            GLL16(bp,                   &Bs[cur ^ 1][wid * 16][0]);
            GLL16(bp + (size_t)64 * KP, &Bs[cur ^ 1][64 + wid * 16][0]);
        }

        bf16x8 af[4], bfr[4];
#pragma unroll
        for (int m = 0; m < 4; ++m)
            af[m] = *(const bf16x8*)&As[wr * 64 + m * 16 + fr16][kb8];
#pragma unroll
        for (int n = 0; n < 4; ++n)
            bfr[n] = *(const bf16x8*)&Bs[cur][wc * 64 + n * 16 + fr16][kb8];
#pragma unroll
        for (int m = 0; m < 4; ++m)
#pragma unroll
            for (int n = 0; n < 4; ++n)
                acc[m][n] = __builtin_amdgcn_mfma_f32_16x16x32_bf16(
                    af[m], bfr[n], acc[m][n], 0, 0, 0);

        __syncthreads();
        cur ^= 1;
    }

    // epilogue: bf16 C write
    const int crow = (lane >> 4) << 2;
#pragma unroll
    for (int m = 0; m < 4; ++m) {
        int rbase = row0 + wr * 64 + m * 16 + crow;
#pragma unroll
        for (int r = 0; r < 4; ++r) {
            int row = rbase + r;
            if (row < M) {
                unsigned short* Yp = Y + (size_t)row * 1024 + col0 + wc * 64 + fr16;
#pragma unroll
                for (int n = 0; n < 4; ++n)
                    Yp[n * 16] = f2bf(acc[m][n][r]);
            }
        }
    }
}

// ---------------- agg1: mean-gather(Yl) + b1 + self(Yr) + BN + ReLU -> h (bf16) ----
__global__ __launch_bounds__(256) void agg1_kernel(
    const unsigned short* __restrict__ Y, unsigned short* __restrict__ Hh,
    const int* __restrict__ row_start, const int* __restrict__ colidx,
    const float* __restrict__ b1, const float* __restrict__ gamma,
    const float* __restrict__ beta, const float* __restrict__ mean,
    const float* __restrict__ var, int n)
{
    int wid  = (blockIdx.x * blockDim.x + threadIdx.x) >> 6;
    int lane = threadIdx.x & 63;
    if (wid >= n) return;
    int c0 = lane * 8;
    float sc[8], sh[8], bb[8];
#pragma unroll
    for (int j = 0; j < 8; ++j) {
        int c = c0 + j;
        sc[j] = gamma[c] * rsqrtf(var[c] + BN_EPS);
        sh[j] = beta[c] - mean[c] * sc[j];
        bb[j] = b1[c];
    }
    int s0 = row_start[wid], s1 = row_start[wid + 1];
    float acc[8] = {0, 0, 0, 0, 0, 0, 0, 0};
    for (int i = s0; i < s1; ++i) {
        int src = colidx[i];
        u16x8 v = *(const u16x8*)&Y[(size_t)src * 1024 + c0];
#pragma unroll
        for (int j = 0; j < 8; ++j) acc[j] += bf2f(v[j]);
    }
    float inv = 1.0f / fmaxf((float)(s1 - s0), 1.0f);
    u16x8 sv = *(const u16x8*)&Y[(size_t)wid * 1024 + 512 + c0];
    unsigned short o[8];
#pragma unroll
    for (int j = 0; j < 8; ++j) {
        float pre = acc[j] * inv + bb[j] + bf2f(sv[j]);
        float h = pre * sc[j] + sh[j];
        o[j] = f2bf(fmaxf(h, 0.0f));
    }
    *(u16x8*)&Hh[(size_t)wid * 512 + c0] = *(u16x8*)o;
}

// ---------------- GEMM2: U[M x 128](bf16) = h[M x 512](bf16) @ BT2^T ------------
// 128x128 tile, both operands via global_load_lds, double-buffered, 1 barrier/iter.
__global__ __launch_bounds__(256) void gemm2_bf16(
    const unsigned short* __restrict__ Hh, int M,
    const unsigned short* __restrict__ BT2,
    unsigned short* __restrict__ U)
{
    __shared__ __align__(16) unsigned short As[2][128][32];
    __shared__ __align__(16) unsigned short Bs[2][128][32];

    const int t    = threadIdx.x;
    const int wid  = t >> 6;
    const int lane = t & 63;
    const int row0 = blockIdx.x << 7;

    // staging chunks: c = j*256 + wid*64 + lane, j=0,1; chunk -> (row=c>>2, off=(c&3)*8)
    const int c_lo = wid * 64 + lane;
    const int c_hi = c_lo + 256;
    int ra = row0 + (c_lo >> 2); if (ra >= M) ra = M - 1;
    int rb = row0 + (c_hi >> 2); if (rb >= M) rb = M - 1;
    const unsigned short* aSrc0 = Hh + (size_t)ra * 512 + ((c_lo & 3) << 3);
    const unsigned short* aSrc1 = Hh + (size_t)rb * 512 + ((c_hi & 3) << 3);
    const unsigned short* bSrc0 = BT2 + (size_t)(c_lo >> 2) * 512 + ((c_lo & 3) << 3);
    const unsigned short* bSrc1 = BT2 + (size_t)(c_hi >> 2) * 512 + ((c_hi & 3) << 3);

    const int wr   = wid >> 1, wc = wid & 1;
    const int fr16 = lane & 15;
    const int kb8  = (lane >> 4) << 3;

    f32x4 acc[4][4];
#pragma unroll
    for (int m = 0; m < 4; ++m)
#pragma unroll
        for (int n = 0; n < 4; ++n) acc[m][n] = (f32x4)0.0f;

#define STAGE2(kt, buf) do {                                                  \
        int ko = (kt) * 32;                                                   \
        GLL16(aSrc0 + ko, (unsigned short*)&As[buf][0][0] + (size_t)(wid * 64) * 8);        \
        GLL16(aSrc1 + ko, (unsigned short*)&As[buf][0][0] + (size_t)(256 + wid * 64) * 8);  \
        GLL16(bSrc0 + ko, (unsigned short*)&Bs[buf][0][0] + (size_t)(wid * 64) * 8);        \
        GLL16(bSrc1 + ko, (unsigned short*)&Bs[buf][0][0] + (size_t)(256 + wid * 64) * 8);  \
    } while (0)

    STAGE2(0, 0);
    int cur = 0;
    for (int it = 0; it < NT2; ++it) {
        __syncthreads();   // stage(it) landed (vmcnt drain); [cur^1] reads done
        if (it + 1 < NT2) STAGE2(it + 1, cur ^ 1);

        bf16x8 af[4], bfr[4];
#pragma unroll
        for (int m = 0; m < 4; ++m)
            af[m] = *(const bf16x8*)&As[cur][wr * 64 + m * 16 + fr16][kb8];
#pragma unroll
        for (int n = 0; n < 4; ++n)
            bfr[n] = *(const bf16x8*)&Bs[cur][wc * 64 + n * 16 + fr16][kb8];
#pragma unroll
        for (int m = 0; m < 4; ++m)
#pragma unroll
            for (int n = 0; n < 4; ++n)
                acc[m][n] = __builtin_amdgcn_mfma_f32_16x16x32_bf16(
                    af[m], bfr[n], acc[m][n], 0, 0, 0);
        cur ^= 1;
    }
#undef STAGE2

    const int crow = (lane >> 4) << 2;
#pragma unroll
    for (int m = 0; m < 4; ++m) {
        int rbase = row0 + wr * 64 + m * 16 + crow;
#pragma unroll
        for (int r = 0; r < 4; ++r) {
            int row = rbase + r;
            if (row < M) {
                unsigned short* Up = U + (size_t)row * 128 + wc * 64 + fr16;
#pragma unroll
                for (int n = 0; n < 4; ++n)
                    Up[n * 16] = f2bf(acc[m][n][r]);
            }
        }
    }
}

// ---------------- agg2: mean-gather(Ul) + b2 + self(Ur) -> out (f32) ----------------
__global__ __launch_bounds__(256) void agg2_kernel(
    const unsigned short* __restrict__ U,
    const int* __restrict__ row_start, const int* __restrict__ colidx,
    const float* __restrict__ b2, float* __restrict__ out, int n)
{
    int wid  = (blockIdx.x * blockDim.x + threadIdx.x) >> 6;
    int lane = threadIdx.x & 63;
    if (wid >= n) return;
    int s0 = row_start[wid], s1 = row_start[wid + 1];
    float acc = 0.f;
    for (int i = s0; i < s1; ++i) {
        int src = colidx[i];
        acc += bf2f(U[(size_t)src * 128 + lane]);
    }
    float inv = 1.0f / fmaxf((float)(s1 - s0), 1.0f);
    float z = acc * inv + b2[lane] + bf2f(U[(size_t)wid * 128 + 64 + lane]);
    out[(size_t)wid * 64 + lane] = z;
}

extern "C" void kernel_launch(void* const* d_in, const int* in_sizes, int n_in,
                              void* d_out, int out_size, void* d_ws, size_t ws_size,
                              hipStream_t stream) {
    const float* x     = (const float*)d_in[0];
    const int*   ei    = (const int*)d_in[1];
    const float* W1l   = (const float*)d_in[2];
    const float* b1    = (const float*)d_in[3];
    const float* W1r   = (const float*)d_in[4];
    const float* gamma = (const float*)d_in[5];
    const float* beta  = (const float*)d_in[6];
    const float* mean  = (const float*)d_in[7];
    const float* var   = (const float*)d_in[8];
    const float* W2l   = (const float*)d_in[9];
    const float* b2    = (const float*)d_in[10];
    const float* W2r   = (const float*)d_in[11];
    float* out = (float*)d_out;

    const int N = in_sizes[0] / 2000;   // 50000
    const int E = in_sizes[1] / 2;      // 800000

    // Workspace (bf16 intermediates, ~175 MB total):
    char* ws = (char*)d_ws;
    unsigned short* Y   = (unsigned short*)ws;                 // N*1024 bf16
    unsigned short* Hh  = Y + (size_t)N * 1024;                // N*512 bf16
    unsigned short* U   = Hh + (size_t)N * 512;                // N*128 bf16
    unsigned short* BT  = U + (size_t)N * 128;                 // 1024*2048 bf16
    unsigned short* BT2 = BT + (size_t)1024 * 2048;            // 128*512 bf16
    int* cnt       = (int*)(BT2 + (size_t)128 * 512);
    int* row_start = cnt + N;
    int* cursor    = row_start + N + 4;
    int* colidx    = cursor + N;                               // E

    hipMemsetAsync(cnt, 0, (size_t)N * sizeof(int), stream);
    hipMemsetAsync(cursor, 0, (size_t)N * sizeof(int), stream);

    prep_bt<<<1024, 256, 0, stream>>>(W1l, W1r, BT);
    prep_bt2<<<32, 256, 0, stream>>>(W2l, W2r, BT2);

    int eb = (E + 255) / 256;
    count_kernel<<<eb, 256, 0, stream>>>(ei, E, cnt);
    scan_kernel<<<1, 1024, 0, stream>>>(cnt, row_start, N);
    fill_kernel<<<eb, 256, 0, stream>>>(ei, E, row_start, cursor, colidx);

    // GEMM1 (bf16 MFMA, XCD-swizzled): Y = x @ [W1l | W1r]
    int nby = (N + 127) / 128;
    gemm1_bf16<<<8 * nby, 256, 0, stream>>>(x, N, BT, Y);

    // agg + b1 + BN + ReLU -> h (bf16)
    agg1_kernel<<<(N + 3) / 4, 256, 0, stream>>>(
        Y, Hh, row_start, colidx, b1, gamma, beta, mean, var, N);

    // GEMM2 (bf16 MFMA): U = h @ [W2l | W2r]
    gemm2_bf16<<<nby, 256, 0, stream>>>(Hh, N, BT2, U);

    // agg + b2 + self -> out (f32)
    agg2_kernel<<<(N + 3) / 4, 256, 0, stream>>>(
        U, row_start, colidx, b2, out, N);
}

// Round 4
// 823.957 us; speedup vs baseline: 3.7132x; 1.0413x over previous
//
#include <hip/hip_runtime.h>

// GraphSAGE encoder, restructured: aggregate AFTER linear maps.
//   N=50000, G=2000, E=800000, H=512, Z=64
// Primary path: x -> bf16 once, GEMM1 = pure-bf16 m97-style (global_load_lds both
// operands, dbuf, 1 barrier/iter, XCD swizzle, T2 LDS swizzle).
// Fallback (if ws too small): round-3 in-kernel-conversion GEMM1.

#define BN_EPS 1e-5f
#define GK 2000      // K of GEMM1
#define KP 2048      // padded K
#define NT1C 63      // ceil(2000/32) for cvt path
#define NT1P 64      // 2048/32 for pure path
#define NT2 16       // 512/32

typedef __attribute__((ext_vector_type(8))) short bf16x8;
typedef __attribute__((ext_vector_type(4))) float f32x4;
typedef unsigned short u16x8 __attribute__((ext_vector_type(8)));

__device__ inline unsigned short f2bf(float f) {
    union { float f; unsigned u; } v; v.f = f;
    unsigned r = (v.u + 0x7fffu + ((v.u >> 16) & 1u)) >> 16;
    return (unsigned short)r;
}
__device__ inline float bf2f(unsigned short u) {
    union { unsigned u; float f; } v; v.u = ((unsigned)u) << 16;
    return v.f;
}

#define GLL16(gp, lp) __builtin_amdgcn_global_load_lds( \
    (const __attribute__((address_space(1))) void*)(gp), \
    (__attribute__((address_space(3))) void*)(lp), 16, 0, 0)

// ---------------- degree histogram ----------------
__global__ void count_kernel(const int* __restrict__ ei, int E, int* __restrict__ cnt) {
    int i = blockIdx.x * blockDim.x + threadIdx.x;
    if (i < E) atomicAdd(&cnt[ei[E + i]], 1);   // dst = ei[1][i]
}

// ---------------- exclusive scan over N counts (single block) ----------------
__global__ __launch_bounds__(1024) void scan_kernel(const int* __restrict__ cnt,
                                                    int* __restrict__ row_start, int n) {
    __shared__ int part[1024];
    int t = threadIdx.x;
    int chunk = (n + 1023) >> 10;
    int lo = t * chunk;
    int hi = lo + chunk; if (hi > n) hi = n;
    int s = 0;
    for (int i = lo; i < hi; ++i) s += cnt[i];
    part[t] = s;
    __syncthreads();
    for (int off = 1; off < 1024; off <<= 1) {
        int add = (t >= off) ? part[t - off] : 0;
        __syncthreads();
        part[t] += add;
        __syncthreads();
    }
    int run = (t == 0) ? 0 : part[t - 1];
    for (int i = lo; i < hi; ++i) { row_start[i] = run; run += cnt[i]; }
    if (t == 1023) row_start[n] = part[1023];
}

// ---------------- CSR fill ----------------
__global__ void fill_kernel(const int* __restrict__ ei, int E,
                            const int* __restrict__ row_start,
                            int* __restrict__ cursor, int* __restrict__ colidx) {
    int i = blockIdx.x * blockDim.x + threadIdx.x;
    if (i < E) {
        int d = ei[E + i];
        int p = atomicAdd(&cursor[d], 1);
        colidx[row_start[d] + p] = ei[i];   // src
    }
}

// ---------------- x [M][2000] f32 -> xb [M][2048] bf16 (zero-padded) -------------
__global__ __launch_bounds__(256) void conv_kernel(const float* __restrict__ x,
                                                   unsigned short* __restrict__ xb) {
    int row = blockIdx.x;
    int k8 = threadIdx.x;   // group of 8; 250 valid, 6 pad
    unsigned short us[8];
    if (k8 < 250) {
        const float4* p = (const float4*)(x + (size_t)row * 2000 + k8 * 8);
        float4 v0 = p[0], v1 = p[1];
        us[0]=f2bf(v0.x); us[1]=f2bf(v0.y); us[2]=f2bf(v0.z); us[3]=f2bf(v0.w);
        us[4]=f2bf(v1.x); us[5]=f2bf(v1.y); us[6]=f2bf(v1.z); us[7]=f2bf(v1.w);
    } else {
#pragma unroll
        for (int j = 0; j < 8; ++j) us[j] = 0;
    }
    *(u16x8*)&xb[(size_t)row * 2048 + k8 * 8] = *(u16x8*)us;
}

// ---------------- BT1[1024][2048] bf16 = [W1l|W1r]^T, zero-padded ----------------
__global__ __launch_bounds__(256) void prep_bt(const float* __restrict__ W1l,
                                               const float* __restrict__ W1r,
                                               unsigned short* __restrict__ BT) {
    int idx = blockIdx.x * 256 + threadIdx.x;
    int c  = idx >> 8;
    int k0 = (idx & 255) << 3;
    const float* W = (c < 512) ? (W1l + c) : (W1r + (c - 512));
    unsigned short us[8];
#pragma unroll
    for (int j = 0; j < 8; ++j) {
        int k = k0 + j;
        float v = (k < GK) ? W[(size_t)k * 512] : 0.0f;
        us[j] = f2bf(v);
    }
    *(u16x8*)&BT[(size_t)c * KP + k0] = *(u16x8*)us;
}

// ---------------- BT2[128][512] bf16 = [W2l|W2r]^T ----------------
__global__ __launch_bounds__(256) void prep_bt2(const float* __restrict__ W2l,
                                                const float* __restrict__ W2r,
                                                unsigned short* __restrict__ BT2) {
    int idx = blockIdx.x * 256 + threadIdx.x;
    int c  = idx >> 6;
    int k0 = (idx & 63) << 3;
    const float* W = (c < 64) ? (W2l + c) : (W2r + (c - 64));
    unsigned short us[8];
#pragma unroll
    for (int j = 0; j < 8; ++j) us[j] = f2bf(W[(size_t)(k0 + j) * 64]);
    *(u16x8*)&BT2[(size_t)c * 512 + k0] = *(u16x8*)us;
}

// ---------------- GEMM1 primary: Y = xb(bf16) @ BT^T, pure gload_lds ------------
// 128x128 tile, 4 waves (2x2 of 64x64), BK=32, 1 barrier/iter, dbuf A+B,
// T2 swizzle: stored[row][g] = tile[row][g ^ (row&3)] (16B granules).
__global__ __launch_bounds__(256) void gemm1_pure(
    const unsigned short* __restrict__ xb, int M,
    const unsigned short* __restrict__ BT,
    unsigned short* __restrict__ Y)
{
    __shared__ __align__(16) unsigned short As[2][4096];
    __shared__ __align__(16) unsigned short Bs[2][4096];

    const int t = threadIdx.x, wid = t >> 6, lane = t & 63;
    const int nby = (M + 127) >> 7;
    const int b   = blockIdx.x;
    const int swz = (b & 7) * nby + (b >> 3);     // XCD-bijective (nwg = 8*nby)
    const int row0 = (swz >> 3) << 7;
    const int col0 = (swz & 7) << 7;

    // staging chunks c (16B each): c = j*256 + wid*64 + lane; row=c>>2, g=c&3
    const int c0 = wid * 64 + lane, c1 = c0 + 256;
    const int g0 = ((c0 & 3) ^ ((c0 >> 2) & 3)) << 3;   // pre-swizzled src granule (elems)
    const int g1 = ((c1 & 3) ^ ((c1 >> 2) & 3)) << 3;
    int ra0 = row0 + (c0 >> 2); if (ra0 >= M) ra0 = M - 1;
    int ra1 = row0 + (c1 >> 2); if (ra1 >= M) ra1 = M - 1;
    const unsigned short* aS0 = xb + (size_t)ra0 * KP + g0;
    const unsigned short* aS1 = xb + (size_t)ra1 * KP + g1;
    const unsigned short* bS0 = BT + (size_t)(col0 + (c0 >> 2)) * KP + g0;
    const unsigned short* bS1 = BT + (size_t)(col0 + (c1 >> 2)) * KP + g1;

    const int wr = wid >> 1, wc = wid & 1;
    const int fr16 = lane & 15;
    // swizzled read granule byte offset (constant per thread)
    const int gswr = ((lane >> 4) ^ (fr16 & 3)) << 4;

    f32x4 acc[4][4];
#pragma unroll
    for (int m = 0; m < 4; ++m)
#pragma unroll
        for (int n = 0; n < 4; ++n) acc[m][n] = (f32x4)0.0f;

#define STG1(kt, buf) do {                                          \
        GLL16(aS0 + (size_t)(kt) * 32, &As[buf][(wid * 64) * 8]);         \
        GLL16(aS1 + (size_t)(kt) * 32, &As[buf][(256 + wid * 64) * 8]);   \
        GLL16(bS0 + (size_t)(kt) * 32, &Bs[buf][(wid * 64) * 8]);         \
        GLL16(bS1 + (size_t)(kt) * 32, &Bs[buf][(256 + wid * 64) * 8]);   \
    } while (0)

    STG1(0, 0);
    int cur = 0;
    for (int it = 0; it < NT1P; ++it) {
        __syncthreads();                 // stage(it) landed; prev reads drained
        if (it + 1 < NT1P) STG1(it + 1, cur ^ 1);

        const char* Ab = (const char*)&As[cur][0];
        const char* Bb = (const char*)&Bs[cur][0];
        bf16x8 af[4], bfr[4];
#pragma unroll
        for (int m = 0; m < 4; ++m)
            af[m] = *(const bf16x8*)(Ab + ((wr * 64 + m * 16 + fr16) << 6) + gswr);
#pragma unroll
        for (int n = 0; n < 4; ++n)
            bfr[n] = *(const bf16x8*)(Bb + ((wc * 64 + n * 16 + fr16) << 6) + gswr);
#pragma unroll
        for (int m = 0; m < 4; ++m)
#pragma unroll
            for (int n = 0; n < 4; ++n)
                acc[m][n] = __builtin_amdgcn_mfma_f32_16x16x32_bf16(
                    af[m], bfr[n], acc[m][n], 0, 0, 0);
        cur ^= 1;
    }
#undef STG1

    const int crow = (lane >> 4) << 2;
#pragma unroll
    for (int m = 0; m < 4; ++m) {
        int rbase = row0 + wr * 64 + m * 16 + crow;
#pragma unroll
        for (int r = 0; r < 4; ++r) {
            int row = rbase + r;
            if (row < M) {
                unsigned short* Yp = Y + (size_t)row * 1024 + col0 + wc * 64 + fr16;
#pragma unroll
                for (int n = 0; n < 4; ++n)
                    Yp[n * 16] = f2bf(acc[m][n][r]);
            }
        }
    }
}

// ---------------- GEMM1 fallback (round-3, in-kernel f32->bf16) ----------------
__global__ __launch_bounds__(256) void gemm1_cvt(
    const float* __restrict__ A, int M,
    const unsigned short* __restrict__ BT,
    unsigned short* __restrict__ Y)
{
    __shared__ __align__(16) unsigned short As[128][32];
    __shared__ __align__(16) unsigned short Bs[2][128][32];

    const int t    = threadIdx.x;
    const int wid  = t >> 6;
    const int lane = t & 63;
    const int nby = (M + 127) >> 7;
    const int b   = blockIdx.x;
    const int swz = (b & 7) * nby + (b >> 3);
    const int row0 = (swz >> 3) << 7;
    const int col0 = (swz & 7) << 7;

    const int ar  = t >> 1;
    const int akq = (t & 1) << 4;
    int garow = row0 + ar; if (garow >= M) garow = M - 1;
    const float* aptr = A + (size_t)garow * GK + akq;

    const int i0 = wid * 64 + lane;
    const unsigned short* bptr0 = BT + ((size_t)(col0 + (i0 >> 2)) * KP + ((i0 & 3) << 3));
    const unsigned short* bptr1 = bptr0 + (size_t)64 * KP;

    const int wr   = wid >> 1, wc = wid & 1;
    const int fr16 = lane & 15;
    const int kb8  = (lane >> 4) << 3;

    f32x4 acc[4][4];
#pragma unroll
    for (int m = 0; m < 4; ++m)
#pragma unroll
        for (int n = 0; n < 4; ++n) acc[m][n] = (f32x4)0.0f;

    GLL16(bptr0, &Bs[0][wid * 16][0]);
    GLL16(bptr1, &Bs[0][64 + wid * 16][0]);

    float frg[16];
    {
        const float4* p = (const float4*)aptr;
        float4 v0 = p[0], v1 = p[1], v2 = p[2], v3 = p[3];
        frg[0]=v0.x; frg[1]=v0.y; frg[2]=v0.z;  frg[3]=v0.w;
        frg[4]=v1.x; frg[5]=v1.y; frg[6]=v1.z;  frg[7]=v1.w;
        frg[8]=v2.x; frg[9]=v2.y; frg[10]=v2.z; frg[11]=v2.w;
        frg[12]=v3.x;frg[13]=v3.y;frg[14]=v3.z; frg[15]=v3.w;
    }

    int cur = 0;
    for (int it = 0; it < NT1C; ++it) {
        {
            unsigned short us[16];
#pragma unroll
            for (int j = 0; j < 16; ++j) us[j] = f2bf(frg[j]);
            *(u16x8*)&As[ar][akq]     = *(u16x8*)&us[0];
            *(u16x8*)&As[ar][akq + 8] = *(u16x8*)&us[8];
        }
        __syncthreads();

        if (it + 1 < NT1C) {
            int kb = (it + 1) * 32 + akq;
            if (kb < GK) {
                const float4* p = (const float4*)(aptr + (size_t)(it + 1) * 32);
                float4 v0 = p[0], v1 = p[1], v2 = p[2], v3 = p[3];
                frg[0]=v0.x; frg[1]=v0.y; frg[2]=v0.z;  frg[3]=v0.w;
                frg[4]=v1.x; frg[5]=v1.y; frg[6]=v1.z;  frg[7]=v1.w;
                frg[8]=v2.x; frg[9]=v2.y; frg[10]=v2.z; frg[11]=v2.w;
                frg[12]=v3.x;frg[13]=v3.y;frg[14]=v3.z; frg[15]=v3.w;
            } else {
#pragma unroll
                for (int j = 0; j < 16; ++j) frg[j] = 0.0f;
            }
            const unsigned short* bp = bptr0 + (size_t)(it + 1) * 32;
            GLL16(bp,                   &Bs[cur ^ 1][wid * 16][0]);
            GLL16(bp + (size_t)64 * KP, &Bs[cur ^ 1][64 + wid * 16][0]);
        }

        bf16x8 af[4], bfr[4];
#pragma unroll
        for (int m = 0; m < 4; ++m)
            af[m] = *(const bf16x8*)&As[wr * 64 + m * 16 + fr16][kb8];
#pragma unroll
        for (int n = 0; n < 4; ++n)
            bfr[n] = *(const bf16x8*)&Bs[cur][wc * 64 + n * 16 + fr16][kb8];
#pragma unroll
        for (int m = 0; m < 4; ++m)
#pragma unroll
            for (int n = 0; n < 4; ++n)
                acc[m][n] = __builtin_amdgcn_mfma_f32_16x16x32_bf16(
                    af[m], bfr[n], acc[m][n], 0, 0, 0);

        __syncthreads();
        cur ^= 1;
    }

    const int crow = (lane >> 4) << 2;
#pragma unroll
    for (int m = 0; m < 4; ++m) {
        int rbase = row0 + wr * 64 + m * 16 + crow;
#pragma unroll
        for (int r = 0; r < 4; ++r) {
            int row = rbase + r;
            if (row < M) {
                unsigned short* Yp = Y + (size_t)row * 1024 + col0 + wc * 64 + fr16;
#pragma unroll
                for (int n = 0; n < 4; ++n)
                    Yp[n * 16] = f2bf(acc[m][n][r]);
            }
        }
    }
}

// ---------------- agg1: mean-gather(Yl) + b1 + self(Yr) + BN + ReLU -> h (bf16) ----
__global__ __launch_bounds__(256) void agg1_kernel(
    const unsigned short* __restrict__ Y, unsigned short* __restrict__ Hh,
    const int* __restrict__ row_start, const int* __restrict__ colidx,
    const float* __restrict__ b1, const float* __restrict__ gamma,
    const float* __restrict__ beta, const float* __restrict__ mean,
    const float* __restrict__ var, int n)
{
    int wid  = (blockIdx.x * blockDim.x + threadIdx.x) >> 6;
    int lane = threadIdx.x & 63;
    if (wid >= n) return;
    int c0 = lane * 8;
    float sc[8], sh[8], bb[8];
#pragma unroll
    for (int j = 0; j < 8; ++j) {
        int c = c0 + j;
        sc[j] = gamma[c] * rsqrtf(var[c] + BN_EPS);
        sh[j] = beta[c] - mean[c] * sc[j];
        bb[j] = b1[c];
    }
    int s0 = row_start[wid], s1 = row_start[wid + 1];
    float acc[8] = {0, 0, 0, 0, 0, 0, 0, 0};
    for (int i = s0; i < s1; ++i) {
        int src = colidx[i];
        u16x8 v = *(const u16x8*)&Y[(size_t)src * 1024 + c0];
#pragma unroll
        for (int j = 0; j < 8; ++j) acc[j] += bf2f(v[j]);
    }
    float inv = 1.0f / fmaxf((float)(s1 - s0), 1.0f);
    u16x8 sv = *(const u16x8*)&Y[(size_t)wid * 1024 + 512 + c0];
    unsigned short o[8];
#pragma unroll
    for (int j = 0; j < 8; ++j) {
        float pre = acc[j] * inv + bb[j] + bf2f(sv[j]);
        float h = pre * sc[j] + sh[j];
        o[j] = f2bf(fmaxf(h, 0.0f));
    }
    *(u16x8*)&Hh[(size_t)wid * 512 + c0] = *(u16x8*)o;
}

// ---------------- GEMM2: U[M x 128](bf16) = h[M x 512](bf16) @ BT2^T ------------
__global__ __launch_bounds__(256) void gemm2_bf16(
    const unsigned short* __restrict__ Hh, int M,
    const unsigned short* __restrict__ BT2,
    unsigned short* __restrict__ U)
{
    __shared__ __align__(16) unsigned short As[2][128][32];
    __shared__ __align__(16) unsigned short Bs[2][128][32];

    const int t    = threadIdx.x;
    const int wid  = t >> 6;
    const int lane = t & 63;
    const int row0 = blockIdx.x << 7;

    const int c_lo = wid * 64 + lane;
    const int c_hi = c_lo + 256;
    int ra = row0 + (c_lo >> 2); if (ra >= M) ra = M - 1;
    int rb = row0 + (c_hi >> 2); if (rb >= M) rb = M - 1;
    const unsigned short* aSrc0 = Hh + (size_t)ra * 512 + ((c_lo & 3) << 3);
    const unsigned short* aSrc1 = Hh + (size_t)rb * 512 + ((c_hi & 3) << 3);
    const unsigned short* bSrc0 = BT2 + (size_t)(c_lo >> 2) * 512 + ((c_lo & 3) << 3);
    const unsigned short* bSrc1 = BT2 + (size_t)(c_hi >> 2) * 512 + ((c_hi & 3) << 3);

    const int wr   = wid >> 1, wc = wid & 1;
    const int fr16 = lane & 15;
    const int kb8  = (lane >> 4) << 3;

    f32x4 acc[4][4];
#pragma unroll
    for (int m = 0; m < 4; ++m)
#pragma unroll
        for (int n = 0; n < 4; ++n) acc[m][n] = (f32x4)0.0f;

#define STAGE2(kt, buf) do {                                                  \
        int ko = (kt) * 32;                                                   \
        GLL16(aSrc0 + ko, (unsigned short*)&As[buf][0][0] + (size_t)(wid * 64) * 8);        \
        GLL16(aSrc1 + ko, (unsigned short*)&As[buf][0][0] + (size_t)(256 + wid * 64) * 8);  \
        GLL16(bSrc0 + ko, (unsigned short*)&Bs[buf][0][0] + (size_t)(wid * 64) * 8);        \
        GLL16(bSrc1 + ko, (unsigned short*)&Bs[buf][0][0] + (size_t)(256 + wid * 64) * 8);  \
    } while (0)

    STAGE2(0, 0);
    int cur = 0;
    for (int it = 0; it < NT2; ++it) {
        __syncthreads();
        if (it + 1 < NT2) STAGE2(it + 1, cur ^ 1);

        bf16x8 af[4], bfr[4];
#pragma unroll
        for (int m = 0; m < 4; ++m)
            af[m] = *(const bf16x8*)&As[cur][wr * 64 + m * 16 + fr16][kb8];
#pragma unroll
        for (int n = 0; n < 4; ++n)
            bfr[n] = *(const bf16x8*)&Bs[cur][wc * 64 + n * 16 + fr16][kb8];
#pragma unroll
        for (int m = 0; m < 4; ++m)
#pragma unroll
            for (int n = 0; n < 4; ++n)
                acc[m][n] = __builtin_amdgcn_mfma_f32_16x16x32_bf16(
                    af[m], bfr[n], acc[m][n], 0, 0, 0);
        cur ^= 1;
    }
#undef STAGE2

    const int crow = (lane >> 4) << 2;
#pragma unroll
    for (int m = 0; m < 4; ++m) {
        int rbase = row0 + wr * 64 + m * 16 + crow;
#pragma unroll
        for (int r = 0; r < 4; ++r) {
            int row = rbase + r;
            if (row < M) {
                unsigned short* Up = U + (size_t)row * 128 + wc * 64 + fr16;
#pragma unroll
                for (int n = 0; n < 4; ++n)
                    Up[n * 16] = f2bf(acc[m][n][r]);
            }
        }
    }
}

// ---------------- agg2: mean-gather(Ul) + b2 + self(Ur) -> out (f32) ----------------
__global__ __launch_bounds__(256) void agg2_kernel(
    const unsigned short* __restrict__ U,
    const int* __restrict__ row_start, const int* __restrict__ colidx,
    const float* __restrict__ b2, float* __restrict__ out, int n)
{
    int wid  = (blockIdx.x * blockDim.x + threadIdx.x) >> 6;
    int lane = threadIdx.x & 63;
    if (wid >= n) return;
    int s0 = row_start[wid], s1 = row_start[wid + 1];
    float acc = 0.f;
    for (int i = s0; i < s1; ++i) {
        int src = colidx[i];
        acc += bf2f(U[(size_t)src * 128 + lane]);
    }
    float inv = 1.0f / fmaxf((float)(s1 - s0), 1.0f);
    float z = acc * inv + b2[lane] + bf2f(U[(size_t)wid * 128 + 64 + lane]);
    out[(size_t)wid * 64 + lane] = z;
}

extern "C" void kernel_launch(void* const* d_in, const int* in_sizes, int n_in,
                              void* d_out, int out_size, void* d_ws, size_t ws_size,
                              hipStream_t stream) {
    const float* x     = (const float*)d_in[0];
    const int*   ei    = (const int*)d_in[1];
    const float* W1l   = (const float*)d_in[2];
    const float* b1    = (const float*)d_in[3];
    const float* W1r   = (const float*)d_in[4];
    const float* gamma = (const float*)d_in[5];
    const float* beta  = (const float*)d_in[6];
    const float* mean  = (const float*)d_in[7];
    const float* var   = (const float*)d_in[8];
    const float* W2l   = (const float*)d_in[9];
    const float* b2    = (const float*)d_in[10];
    const float* W2r   = (const float*)d_in[11];
    float* out = (float*)d_out;

    const int N = in_sizes[0] / 2000;   // 50000
    const int E = in_sizes[1] / 2;      // 800000
    const int nby = (N + 127) / 128;

    char* ws = (char*)d_ws;

    // Primary layout: xb | Y | BT | BT2 | cnt | row_start | cursor | colidx
    //   (Hh aliases xb after gemm1; U aliases Y after agg1)
    size_t need = (size_t)N * KP * 2 + (size_t)N * 1024 * 2
                + (size_t)1024 * KP * 2 + (size_t)128 * 512 * 2
                + ((size_t)3 * N + 8 + (size_t)E) * 4;

    if (ws_size >= need) {
        unsigned short* xb  = (unsigned short*)ws;                 // N*2048 bf16
        unsigned short* Y   = xb + (size_t)N * KP;                 // N*1024 bf16
        unsigned short* BT  = Y + (size_t)N * 1024;                // 1024*2048 bf16
        unsigned short* BT2 = BT + (size_t)1024 * KP;              // 128*512 bf16
        int* cnt       = (int*)(BT2 + (size_t)128 * 512);
        int* row_start = cnt + N;
        int* cursor    = row_start + N + 4;
        int* colidx    = cursor + N;
        unsigned short* Hh = xb;   // alias: xb dead after gemm1
        unsigned short* U  = Y;    // alias: Y dead after agg1

        hipMemsetAsync(cnt, 0, (size_t)N * sizeof(int), stream);
        hipMemsetAsync(cursor, 0, (size_t)N * sizeof(int), stream);

        prep_bt<<<1024, 256, 0, stream>>>(W1l, W1r, BT);
        prep_bt2<<<32, 256, 0, stream>>>(W2l, W2r, BT2);
        conv_kernel<<<N, 256, 0, stream>>>(x, xb);

        int eb = (E + 255) / 256;
        count_kernel<<<eb, 256, 0, stream>>>(ei, E, cnt);
        scan_kernel<<<1, 1024, 0, stream>>>(cnt, row_start, N);
        fill_kernel<<<eb, 256, 0, stream>>>(ei, E, row_start, cursor, colidx);

        gemm1_pure<<<8 * nby, 256, 0, stream>>>(xb, N, BT, Y);
        agg1_kernel<<<(N + 3) / 4, 256, 0, stream>>>(
            Y, Hh, row_start, colidx, b1, gamma, beta, mean, var, N);
        gemm2_bf16<<<nby, 256, 0, stream>>>(Hh, N, BT2, U);
        agg2_kernel<<<(N + 3) / 4, 256, 0, stream>>>(
            U, row_start, colidx, b2, out, N);
    } else {
        // Fallback: round-3 layout and kernels
        unsigned short* Y   = (unsigned short*)ws;                 // N*1024 bf16
        unsigned short* Hh  = Y + (size_t)N * 1024;                // N*512 bf16
        unsigned short* U   = Hh + (size_t)N * 512;                // N*128 bf16
        unsigned short* BT  = U + (size_t)N * 128;                 // 1024*2048 bf16
        unsigned short* BT2 = BT + (size_t)1024 * KP;              // 128*512 bf16
        int* cnt       = (int*)(BT2 + (size_t)128 * 512);
        int* row_start = cnt + N;
        int* cursor    = row_start + N + 4;
        int* colidx    = cursor + N;

        hipMemsetAsync(cnt, 0, (size_t)N * sizeof(int), stream);
        hipMemsetAsync(cursor, 0, (size_t)N * sizeof(int), stream);

        prep_bt<<<1024, 256, 0, stream>>>(W1l, W1r, BT);
        prep_bt2<<<32, 256, 0, stream>>>(W2l, W2r, BT2);

        int eb = (E + 255) / 256;
        count_kernel<<<eb, 256, 0, stream>>>(ei, E, cnt);
        scan_kernel<<<1, 1024, 0, stream>>>(cnt, row_start, N);
        fill_kernel<<<eb, 256, 0, stream>>>(ei, E, row_start, cursor, colidx);

        gemm1_cvt<<<8 * nby, 256, 0, stream>>>(x, N, BT, Y);
        agg1_kernel<<<(N + 3) / 4, 256, 0, stream>>>(
            Y, Hh, row_start, colidx, b1, gamma, beta, mean, var, N);
        gemm2_bf16<<<nby, 256, 0, stream>>>(Hh, N, BT2, U);
        agg2_kernel<<<(N + 3) / 4, 256, 0, stream>>>(
            U, row_start, colidx, b2, out, N);
    }
}

// Round 5
// 779.001 us; speedup vs baseline: 3.9275x; 1.0577x over previous
//
#include <hip/hip_runtime.h>

// GraphSAGE encoder, restructured: aggregate AFTER linear maps.
//   N=50000, G=2000, E=800000, H=512, Z=64
// GEMM1: bf16 MFMA 128x128 tile, 3-ring LDS pipeline with counted vmcnt (T3/T4),
//        raw s_barrier (1/iter), setprio around MFMA (T5), XCD swizzle (T1).
// agg1 / GEMM2 / agg2: all-bf16 intermediate dataflow, fp32 accumulation.

#define BN_EPS 1e-5f
#define GK 2000      // K of GEMM1
#define KP 2048      // padded K
#define NT1C 63      // ceil(2000/32) for cvt fallback path
#define NT1P 64      // 2048/32 for pure path
#define NT2 16       // 512/32

typedef __attribute__((ext_vector_type(8))) short bf16x8;
typedef __attribute__((ext_vector_type(4))) float f32x4;
typedef unsigned short u16x8 __attribute__((ext_vector_type(8)));

__device__ inline unsigned short f2bf(float f) {
    union { float f; unsigned u; } v; v.f = f;
    unsigned r = (v.u + 0x7fffu + ((v.u >> 16) & 1u)) >> 16;
    return (unsigned short)r;
}
__device__ inline float bf2f(unsigned short u) {
    union { unsigned u; float f; } v; v.u = ((unsigned)u) << 16;
    return v.f;
}

#define GLL16(gp, lp) __builtin_amdgcn_global_load_lds( \
    (const __attribute__((address_space(1))) void*)(gp), \
    (__attribute__((address_space(3))) void*)(lp), 16, 0, 0)

// ---------------- degree histogram ----------------
__global__ void count_kernel(const int* __restrict__ ei, int E, int* __restrict__ cnt) {
    int i = blockIdx.x * blockDim.x + threadIdx.x;
    if (i < E) atomicAdd(&cnt[ei[E + i]], 1);   // dst = ei[1][i]
}

// ---------------- exclusive scan over N counts (single block) ----------------
__global__ __launch_bounds__(1024) void scan_kernel(const int* __restrict__ cnt,
                                                    int* __restrict__ row_start, int n) {
    __shared__ int part[1024];
    int t = threadIdx.x;
    int chunk = (n + 1023) >> 10;
    int lo = t * chunk;
    int hi = lo + chunk; if (hi > n) hi = n;
    int s = 0;
    for (int i = lo; i < hi; ++i) s += cnt[i];
    part[t] = s;
    __syncthreads();
    for (int off = 1; off < 1024; off <<= 1) {
        int add = (t >= off) ? part[t - off] : 0;
        __syncthreads();
        part[t] += add;
        __syncthreads();
    }
    int run = (t == 0) ? 0 : part[t - 1];
    for (int i = lo; i < hi; ++i) { row_start[i] = run; run += cnt[i]; }
    if (t == 1023) row_start[n] = part[1023];
}

// ---------------- CSR fill ----------------
__global__ void fill_kernel(const int* __restrict__ ei, int E,
                            const int* __restrict__ row_start,
                            int* __restrict__ cursor, int* __restrict__ colidx) {
    int i = blockIdx.x * blockDim.x + threadIdx.x;
    if (i < E) {
        int d = ei[E + i];
        int p = atomicAdd(&cursor[d], 1);
        colidx[row_start[d] + p] = ei[i];   // src
    }
}

// ---------------- x [M][2000] f32 -> xb [M][2048] bf16 (zero-padded) -------------
__global__ __launch_bounds__(256) void conv_kernel(const float* __restrict__ x,
                                                   unsigned short* __restrict__ xb) {
    int row = blockIdx.x;
    int k8 = threadIdx.x;   // group of 8; 250 valid, 6 pad
    unsigned short us[8];
    if (k8 < 250) {
        const float4* p = (const float4*)(x + (size_t)row * 2000 + k8 * 8);
        float4 v0 = p[0], v1 = p[1];
        us[0]=f2bf(v0.x); us[1]=f2bf(v0.y); us[2]=f2bf(v0.z); us[3]=f2bf(v0.w);
        us[4]=f2bf(v1.x); us[5]=f2bf(v1.y); us[6]=f2bf(v1.z); us[7]=f2bf(v1.w);
    } else {
#pragma unroll
        for (int j = 0; j < 8; ++j) us[j] = 0;
    }
    *(u16x8*)&xb[(size_t)row * 2048 + k8 * 8] = *(u16x8*)us;
}

// ---------------- BT1[1024][2048] bf16 = [W1l|W1r]^T, zero-padded ----------------
__global__ __launch_bounds__(256) void prep_bt(const float* __restrict__ W1l,
                                               const float* __restrict__ W1r,
                                               unsigned short* __restrict__ BT) {
    int idx = blockIdx.x * 256 + threadIdx.x;
    int c  = idx >> 8;
    int k0 = (idx & 255) << 3;
    const float* W = (c < 512) ? (W1l + c) : (W1r + (c - 512));
    unsigned short us[8];
#pragma unroll
    for (int j = 0; j < 8; ++j) {
        int k = k0 + j;
        float v = (k < GK) ? W[(size_t)k * 512] : 0.0f;
        us[j] = f2bf(v);
    }
    *(u16x8*)&BT[(size_t)c * KP + k0] = *(u16x8*)us;
}

// ---------------- BT2[128][512] bf16 = [W2l|W2r]^T ----------------
__global__ __launch_bounds__(256) void prep_bt2(const float* __restrict__ W2l,
                                                const float* __restrict__ W2r,
                                                unsigned short* __restrict__ BT2) {
    int idx = blockIdx.x * 256 + threadIdx.x;
    int c  = idx >> 6;
    int k0 = (idx & 63) << 3;
    const float* W = (c < 64) ? (W2l + c) : (W2r + (c - 64));
    unsigned short us[8];
#pragma unroll
    for (int j = 0; j < 8; ++j) us[j] = f2bf(W[(size_t)(k0 + j) * 64]);
    *(u16x8*)&BT2[(size_t)c * 512 + k0] = *(u16x8*)us;
}

// ---------------- GEMM1: Y = xb(bf16) @ BT^T — 3-ring counted-vmcnt pipeline ------
// 128x128 tile, 4 waves (2x2 of 64x64), BK=32.
// Ring of 3 LDS buffers; stage(kt+2) each iter; per iter: vmcnt(4) -> s_barrier ->
// ds_read frags -> stage -> setprio(1) 16xMFMA setprio(0). Never vmcnt(0) in loop
// (except final iter). 48 KB LDS -> 3 blocks/CU.
__global__ __launch_bounds__(256) void gemm1_pure(
    const unsigned short* __restrict__ xb, int M,
    const unsigned short* __restrict__ BT,
    unsigned short* __restrict__ Y)
{
    __shared__ __align__(16) unsigned short As[3][4096];
    __shared__ __align__(16) unsigned short Bs[3][4096];

    const int t = threadIdx.x, wid = t >> 6, lane = t & 63;
    const int nby = (M + 127) >> 7;
    const int b   = blockIdx.x;
    const int swz = (b & 7) * nby + (b >> 3);     // XCD-bijective (nwg = 8*nby)
    const int row0 = (swz >> 3) << 7;
    const int col0 = (swz & 7) << 7;

    // staging chunks c (16B each): c = j*256 + wid*64 + lane; row=c>>2, g=c&3
    const int c0 = wid * 64 + lane, c1 = c0 + 256;
    const int g0 = ((c0 & 3) ^ ((c0 >> 2) & 3)) << 3;   // pre-swizzled src granule (elems)
    const int g1 = ((c1 & 3) ^ ((c1 >> 2) & 3)) << 3;
    int ra0 = row0 + (c0 >> 2); if (ra0 >= M) ra0 = M - 1;
    int ra1 = row0 + (c1 >> 2); if (ra1 >= M) ra1 = M - 1;
    const unsigned short* aS0 = xb + (size_t)ra0 * KP + g0;
    const unsigned short* aS1 = xb + (size_t)ra1 * KP + g1;
    const unsigned short* bS0 = BT + (size_t)(col0 + (c0 >> 2)) * KP + g0;
    const unsigned short* bS1 = BT + (size_t)(col0 + (c1 >> 2)) * KP + g1;

    const int wr = wid >> 1, wc = wid & 1;
    const int fr16 = lane & 15;
    // swizzled read granule byte offset (constant per thread)
    const int gswr = ((lane >> 4) ^ (fr16 & 3)) << 4;

    f32x4 acc[4][4];
#pragma unroll
    for (int m = 0; m < 4; ++m)
#pragma unroll
        for (int n = 0; n < 4; ++n) acc[m][n] = (f32x4)0.0f;

#define STG1(kt, buf) do {                                             \
        unsigned short* ab_ = &As[buf][0];                             \
        unsigned short* bb_ = &Bs[buf][0];                             \
        GLL16(aS0 + (size_t)(kt) * 32, ab_ + (wid * 64) * 8);          \
        GLL16(aS1 + (size_t)(kt) * 32, ab_ + (256 + wid * 64) * 8);    \
        GLL16(bS0 + (size_t)(kt) * 32, bb_ + (wid * 64) * 8);          \
        GLL16(bS1 + (size_t)(kt) * 32, bb_ + (256 + wid * 64) * 8);    \
    } while (0)

    // prologue: stage tiles 0 and 1 (8 loads/wave outstanding)
    STG1(0, 0);
    STG1(1, 1);

    int rb = 0;   // read buffer = it % 3
    for (int it = 0; it < NT1P; ++it) {
        // wait my 4 oldest loads (tile 'it') -> then barrier proves ALL waves'
        // portions of buf rb landed. Counted: 4 loads (tile it+1) stay in flight.
        if (it == NT1P - 1) {
            asm volatile("s_waitcnt vmcnt(0)" ::: "memory");
        } else {
            asm volatile("s_waitcnt vmcnt(4)" ::: "memory");
        }
        __builtin_amdgcn_s_barrier();
        __builtin_amdgcn_sched_barrier(0);

        const char* Ab = (const char*)&As[rb][0];
        const char* Bb = (const char*)&Bs[rb][0];
        bf16x8 af[4], bfr[4];
#pragma unroll
        for (int m = 0; m < 4; ++m)
            af[m] = *(const bf16x8*)(Ab + ((wr * 64 + m * 16 + fr16) << 6) + gswr);
#pragma unroll
        for (int n = 0; n < 4; ++n)
            bfr[n] = *(const bf16x8*)(Bb + ((wc * 64 + n * 16 + fr16) << 6) + gswr);

        // stage tile it+2 into buf (it+2)%3 (issued after the barrier -> no wave
        // can still be reading that buffer; lands under the next ~2 iters of MFMA)
        if (it + 2 < NT1P) {
            int wb = rb + 2; if (wb >= 3) wb -= 3;
            STG1(it + 2, wb);
        }

        __builtin_amdgcn_s_setprio(1);
#pragma unroll
        for (int m = 0; m < 4; ++m)
#pragma unroll
            for (int n = 0; n < 4; ++n)
                acc[m][n] = __builtin_amdgcn_mfma_f32_16x16x32_bf16(
                    af[m], bfr[n], acc[m][n], 0, 0, 0);
        __builtin_amdgcn_s_setprio(0);

        rb = (rb == 2) ? 0 : rb + 1;
    }
#undef STG1

    const int crow = (lane >> 4) << 2;
#pragma unroll
    for (int m = 0; m < 4; ++m) {
        int rbase = row0 + wr * 64 + m * 16 + crow;
#pragma unroll
        for (int r = 0; r < 4; ++r) {
            int row = rbase + r;
            if (row < M) {
                unsigned short* Yp = Y + (size_t)row * 1024 + col0 + wc * 64 + fr16;
#pragma unroll
                for (int n = 0; n < 4; ++n)
                    Yp[n * 16] = f2bf(acc[m][n][r]);
            }
        }
    }
}

// ---------------- GEMM1 fallback (round-3, in-kernel f32->bf16) ----------------
__global__ __launch_bounds__(256) void gemm1_cvt(
    const float* __restrict__ A, int M,
    const unsigned short* __restrict__ BT,
    unsigned short* __restrict__ Y)
{
    __shared__ __align__(16) unsigned short As[128][32];
    __shared__ __align__(16) unsigned short Bs[2][128][32];

    const int t    = threadIdx.x;
    const int wid  = t >> 6;
    const int lane = t & 63;
    const int nby = (M + 127) >> 7;
    const int b   = blockIdx.x;
    const int swz = (b & 7) * nby + (b >> 3);
    const int row0 = (swz >> 3) << 7;
    const int col0 = (swz & 7) << 7;

    const int ar  = t >> 1;
    const int akq = (t & 1) << 4;
    int garow = row0 + ar; if (garow >= M) garow = M - 1;
    const float* aptr = A + (size_t)garow * GK + akq;

    const int i0 = wid * 64 + lane;
    const unsigned short* bptr0 = BT + ((size_t)(col0 + (i0 >> 2)) * KP + ((i0 & 3) << 3));
    const unsigned short* bptr1 = bptr0 + (size_t)64 * KP;

    const int wr   = wid >> 1, wc = wid & 1;
    const int fr16 = lane & 15;
    const int kb8  = (lane >> 4) << 3;

    f32x4 acc[4][4];
#pragma unroll
    for (int m = 0; m < 4; ++m)
#pragma unroll
        for (int n = 0; n < 4; ++n) acc[m][n] = (f32x4)0.0f;

    GLL16(bptr0, &Bs[0][wid * 16][0]);
    GLL16(bptr1, &Bs[0][64 + wid * 16][0]);

    float frg[16];
    {
        const float4* p = (const float4*)aptr;
        float4 v0 = p[0], v1 = p[1], v2 = p[2], v3 = p[3];
        frg[0]=v0.x; frg[1]=v0.y; frg[2]=v0.z;  frg[3]=v0.w;
        frg[4]=v1.x; frg[5]=v1.y; frg[6]=v1.z;  frg[7]=v1.w;
        frg[8]=v2.x; frg[9]=v2.y; frg[10]=v2.z; frg[11]=v2.w;
        frg[12]=v3.x;frg[13]=v3.y;frg[14]=v3.z; frg[15]=v3.w;
    }

    int cur = 0;
    for (int it = 0; it < NT1C; ++it) {
        {
            unsigned short us[16];
#pragma unroll
            for (int j = 0; j < 16; ++j) us[j] = f2bf(frg[j]);
            *(u16x8*)&As[ar][akq]     = *(u16x8*)&us[0];
            *(u16x8*)&As[ar][akq + 8] = *(u16x8*)&us[8];
        }
        __syncthreads();

        if (it + 1 < NT1C) {
            int kb = (it + 1) * 32 + akq;
            if (kb < GK) {
                const float4* p = (const float4*)(aptr + (size_t)(it + 1) * 32);
                float4 v0 = p[0], v1 = p[1], v2 = p[2], v3 = p[3];
                frg[0]=v0.x; frg[1]=v0.y; frg[2]=v0.z;  frg[3]=v0.w;
                frg[4]=v1.x; frg[5]=v1.y; frg[6]=v1.z;  frg[7]=v1.w;
                frg[8]=v2.x; frg[9]=v2.y; frg[10]=v2.z; frg[11]=v2.w;
                frg[12]=v3.x;frg[13]=v3.y;frg[14]=v3.z; frg[15]=v3.w;
            } else {
#pragma unroll
                for (int j = 0; j < 16; ++j) frg[j] = 0.0f;
            }
            const unsigned short* bp = bptr0 + (size_t)(it + 1) * 32;
            GLL16(bp,                   &Bs[cur ^ 1][wid * 16][0]);
            GLL16(bp + (size_t)64 * KP, &Bs[cur ^ 1][64 + wid * 16][0]);
        }

        bf16x8 af[4], bfr[4];
#pragma unroll
        for (int m = 0; m < 4; ++m)
            af[m] = *(const bf16x8*)&As[wr * 64 + m * 16 + fr16][kb8];
#pragma unroll
        for (int n = 0; n < 4; ++n)
            bfr[n] = *(const bf16x8*)&Bs[cur][wc * 64 + n * 16 + fr16][kb8];
#pragma unroll
        for (int m = 0; m < 4; ++m)
#pragma unroll
            for (int n = 0; n < 4; ++n)
                acc[m][n] = __builtin_amdgcn_mfma_f32_16x16x32_bf16(
                    af[m], bfr[n], acc[m][n], 0, 0, 0);

        __syncthreads();
        cur ^= 1;
    }

    const int crow = (lane >> 4) << 2;
#pragma unroll
    for (int m = 0; m < 4; ++m) {
        int rbase = row0 + wr * 64 + m * 16 + crow;
#pragma unroll
        for (int r = 0; r < 4; ++r) {
            int row = rbase + r;
            if (row < M) {
                unsigned short* Yp = Y + (size_t)row * 1024 + col0 + wc * 64 + fr16;
#pragma unroll
                for (int n = 0; n < 4; ++n)
                    Yp[n * 16] = f2bf(acc[m][n][r]);
            }
        }
    }
}

// ---------------- agg1: mean-gather(Yl) + b1 + self(Yr) + BN + ReLU -> h (bf16) ----
__global__ __launch_bounds__(256) void agg1_kernel(
    const unsigned short* __restrict__ Y, unsigned short* __restrict__ Hh,
    const int* __restrict__ row_start, const int* __restrict__ colidx,
    const float* __restrict__ b1, const float* __restrict__ gamma,
    const float* __restrict__ beta, const float* __restrict__ mean,
    const float* __restrict__ var, int n)
{
    int wid  = (blockIdx.x * blockDim.x + threadIdx.x) >> 6;
    int lane = threadIdx.x & 63;
    if (wid >= n) return;
    int c0 = lane * 8;
    float sc[8], sh[8], bb[8];
#pragma unroll
    for (int j = 0; j < 8; ++j) {
        int c = c0 + j;
        sc[j] = gamma[c] * rsqrtf(var[c] + BN_EPS);
        sh[j] = beta[c] - mean[c] * sc[j];
        bb[j] = b1[c];
    }
    int s0 = row_start[wid], s1 = row_start[wid + 1];
    float acc[8] = {0, 0, 0, 0, 0, 0, 0, 0};
    for (int i = s0; i < s1; ++i) {
        int src = colidx[i];
        u16x8 v = *(const u16x8*)&Y[(size_t)src * 1024 + c0];
#pragma unroll
        for (int j = 0; j < 8; ++j) acc[j] += bf2f(v[j]);
    }
    float inv = 1.0f / fmaxf((float)(s1 - s0), 1.0f);
    u16x8 sv = *(const u16x8*)&Y[(size_t)wid * 1024 + 512 + c0];
    unsigned short o[8];
#pragma unroll
    for (int j = 0; j < 8; ++j) {
        float pre = acc[j] * inv + bb[j] + bf2f(sv[j]);
        float h = pre * sc[j] + sh[j];
        o[j] = f2bf(fmaxf(h, 0.0f));
    }
    *(u16x8*)&Hh[(size_t)wid * 512 + c0] = *(u16x8*)o;
}

// ---------------- GEMM2: U[M x 128](bf16) = h[M x 512](bf16) @ BT2^T ------------
__global__ __launch_bounds__(256) void gemm2_bf16(
    const unsigned short* __restrict__ Hh, int M,
    const unsigned short* __restrict__ BT2,
    unsigned short* __restrict__ U)
{
    __shared__ __align__(16) unsigned short As[2][128][32];
    __shared__ __align__(16) unsigned short Bs[2][128][32];

    const int t    = threadIdx.x;
    const int wid  = t >> 6;
    const int lane = t & 63;
    const int row0 = blockIdx.x << 7;

    const int c_lo = wid * 64 + lane;
    const int c_hi = c_lo + 256;
    int ra = row0 + (c_lo >> 2); if (ra >= M) ra = M - 1;
    int rb = row0 + (c_hi >> 2); if (rb >= M) rb = M - 1;
    const unsigned short* aSrc0 = Hh + (size_t)ra * 512 + ((c_lo & 3) << 3);
    const unsigned short* aSrc1 = Hh + (size_t)rb * 512 + ((c_hi & 3) << 3);
    const unsigned short* bSrc0 = BT2 + (size_t)(c_lo >> 2) * 512 + ((c_lo & 3) << 3);
    const unsigned short* bSrc1 = BT2 + (size_t)(c_hi >> 2) * 512 + ((c_hi & 3) << 3);

    const int wr   = wid >> 1, wc = wid & 1;
    const int fr16 = lane & 15;
    const int kb8  = (lane >> 4) << 3;

    f32x4 acc[4][4];
#pragma unroll
    for (int m = 0; m < 4; ++m)
#pragma unroll
        for (int n = 0; n < 4; ++n) acc[m][n] = (f32x4)0.0f;

#define STAGE2(kt, buf) do {                                                  \
        int ko = (kt) * 32;                                                   \
        GLL16(aSrc0 + ko, (unsigned short*)&As[buf][0][0] + (size_t)(wid * 64) * 8);        \
        GLL16(aSrc1 + ko, (unsigned short*)&As[buf][0][0] + (size_t)(256 + wid * 64) * 8);  \
        GLL16(bSrc0 + ko, (unsigned short*)&Bs[buf][0][0] + (size_t)(wid * 64) * 8);        \
        GLL16(bSrc1 + ko, (unsigned short*)&Bs[buf][0][0] + (size_t)(256 + wid * 64) * 8);  \
    } while (0)

    STAGE2(0, 0);
    int cur = 0;
    for (int it = 0; it < NT2; ++it) {
        __syncthreads();
        if (it + 1 < NT2) STAGE2(it + 1, cur ^ 1);

        bf16x8 af[4], bfr[4];
#pragma unroll
        for (int m = 0; m < 4; ++m)
            af[m] = *(const bf16x8*)&As[cur][wr * 64 + m * 16 + fr16][kb8];
#pragma unroll
        for (int n = 0; n < 4; ++n)
            bfr[n] = *(const bf16x8*)&Bs[cur][wc * 64 + n * 16 + fr16][kb8];
#pragma unroll
        for (int m = 0; m < 4; ++m)
#pragma unroll
            for (int n = 0; n < 4; ++n)
                acc[m][n] = __builtin_amdgcn_mfma_f32_16x16x32_bf16(
                    af[m], bfr[n], acc[m][n], 0, 0, 0);
        cur ^= 1;
    }
#undef STAGE2

    const int crow = (lane >> 4) << 2;
#pragma unroll
    for (int m = 0; m < 4; ++m) {
        int rbase = row0 + wr * 64 + m * 16 + crow;
#pragma unroll
        for (int r = 0; r < 4; ++r) {
            int row = rbase + r;
            if (row < M) {
                unsigned short* Up = U + (size_t)row * 128 + wc * 64 + fr16;
#pragma unroll
                for (int n = 0; n < 4; ++n)
                    Up[n * 16] = f2bf(acc[m][n][r]);
            }
        }
    }
}

// ---------------- agg2: mean-gather(Ul) + b2 + self(Ur) -> out (f32) ----------------
__global__ __launch_bounds__(256) void agg2_kernel(
    const unsigned short* __restrict__ U,
    const int* __restrict__ row_start, const int* __restrict__ colidx,
    const float* __restrict__ b2, float* __restrict__ out, int n)
{
    int wid  = (blockIdx.x * blockDim.x + threadIdx.x) >> 6;
    int lane = threadIdx.x & 63;
    if (wid >= n) return;
    int s0 = row_start[wid], s1 = row_start[wid + 1];
    float acc = 0.f;
    for (int i = s0; i < s1; ++i) {
        int src = colidx[i];
        acc += bf2f(U[(size_t)src * 128 + lane]);
    }
    float inv = 1.0f / fmaxf((float)(s1 - s0), 1.0f);
    float z = acc * inv + b2[lane] + bf2f(U[(size_t)wid * 128 + 64 + lane]);
    out[(size_t)wid * 64 + lane] = z;
}

extern "C" void kernel_launch(void* const* d_in, const int* in_sizes, int n_in,
                              void* d_out, int out_size, void* d_ws, size_t ws_size,
                              hipStream_t stream) {
    const float* x     = (const float*)d_in[0];
    const int*   ei    = (const int*)d_in[1];
    const float* W1l   = (const float*)d_in[2];
    const float* b1    = (const float*)d_in[3];
    const float* W1r   = (const float*)d_in[4];
    const float* gamma = (const float*)d_in[5];
    const float* beta  = (const float*)d_in[6];
    const float* mean  = (const float*)d_in[7];
    const float* var   = (const float*)d_in[8];
    const float* W2l   = (const float*)d_in[9];
    const float* b2    = (const float*)d_in[10];
    const float* W2r   = (const float*)d_in[11];
    float* out = (float*)d_out;

    const int N = in_sizes[0] / 2000;   // 50000
    const int E = in_sizes[1] / 2;      // 800000
    const int nby = (N + 127) / 128;

    char* ws = (char*)d_ws;

    // Primary layout: xb | Y | BT | BT2 | cnt | row_start | cursor | colidx
    //   (Hh aliases xb after gemm1; U aliases Y after agg1)
    size_t need = (size_t)N * KP * 2 + (size_t)N * 1024 * 2
                + (size_t)1024 * KP * 2 + (size_t)128 * 512 * 2
                + ((size_t)3 * N + 8 + (size_t)E) * 4;

    if (ws_size >= need) {
        unsigned short* xb  = (unsigned short*)ws;                 // N*2048 bf16
        unsigned short* Y   = xb + (size_t)N * KP;                 // N*1024 bf16
        unsigned short* BT  = Y + (size_t)N * 1024;                // 1024*2048 bf16
        unsigned short* BT2 = BT + (size_t)1024 * KP;              // 128*512 bf16
        int* cnt       = (int*)(BT2 + (size_t)128 * 512);
        int* row_start = cnt + N;
        int* cursor    = row_start + N + 4;
        int* colidx    = cursor + N;
        unsigned short* Hh = xb;   // alias: xb dead after gemm1
        unsigned short* U  = Y;    // alias: Y dead after agg1

        hipMemsetAsync(cnt, 0, (size_t)N * sizeof(int), stream);
        hipMemsetAsync(cursor, 0, (size_t)N * sizeof(int), stream);

        prep_bt<<<1024, 256, 0, stream>>>(W1l, W1r, BT);
        prep_bt2<<<32, 256, 0, stream>>>(W2l, W2r, BT2);
        conv_kernel<<<N, 256, 0, stream>>>(x, xb);

        int eb = (E + 255) / 256;
        count_kernel<<<eb, 256, 0, stream>>>(ei, E, cnt);
        scan_kernel<<<1, 1024, 0, stream>>>(cnt, row_start, N);
        fill_kernel<<<eb, 256, 0, stream>>>(ei, E, row_start, cursor, colidx);

        gemm1_pure<<<8 * nby, 256, 0, stream>>>(xb, N, BT, Y);
        agg1_kernel<<<(N + 3) / 4, 256, 0, stream>>>(
            Y, Hh, row_start, colidx, b1, gamma, beta, mean, var, N);
        gemm2_bf16<<<nby, 256, 0, stream>>>(Hh, N, BT2, U);
        agg2_kernel<<<(N + 3) / 4, 256, 0, stream>>>(
            U, row_start, colidx, b2, out, N);
    } else {
        // Fallback: round-3 layout and kernels
        unsigned short* Y   = (unsigned short*)ws;                 // N*1024 bf16
        unsigned short* Hh  = Y + (size_t)N * 1024;                // N*512 bf16
        unsigned short* U   = Hh + (size_t)N * 512;                // N*128 bf16
        unsigned short* BT  = U + (size_t)N * 128;                 // 1024*2048 bf16
        unsigned short* BT2 = BT + (size_t)1024 * KP;              // 128*512 bf16
        int* cnt       = (int*)(BT2 + (size_t)128 * 512);
        int* row_start = cnt + N;
        int* cursor    = row_start + N + 4;
        int* colidx    = cursor + N;

        hipMemsetAsync(cnt, 0, (size_t)N * sizeof(int), stream);
        hipMemsetAsync(cursor, 0, (size_t)N * sizeof(int), stream);

        prep_bt<<<1024, 256, 0, stream>>>(W1l, W1r, BT);
        prep_bt2<<<32, 256, 0, stream>>>(W2l, W2r, BT2);

        int eb = (E + 255) / 256;
        count_kernel<<<eb, 256, 0, stream>>>(ei, E, cnt);
        scan_kernel<<<1, 1024, 0, stream>>>(cnt, row_start, N);
        fill_kernel<<<eb, 256, 0, stream>>>(ei, E, row_start, cursor, colidx);

        gemm1_cvt<<<8 * nby, 256, 0, stream>>>(x, N, BT, Y);
        agg1_kernel<<<(N + 3) / 4, 256, 0, stream>>>(
            Y, Hh, row_start, colidx, b1, gamma, beta, mean, var, N);
        gemm2_bf16<<<nby, 256, 0, stream>>>(Hh, N, BT2, U);
        agg2_kernel<<<(N + 3) / 4, 256, 0, stream>>>(
            U, row_start, colidx, b2, out, N);
    }
}

// Round 6
// 771.106 us; speedup vs baseline: 3.9677x; 1.0102x over previous
//
#include <hip/hip_runtime.h>

// GraphSAGE encoder, restructured: aggregate AFTER linear maps.
//   N=50000, G=2000, E=800000, H=512, Z=64
// GEMM1: bf16 MFMA 256x256 tile, 8 waves (2x4 of 128x64), 3-ring LDS pipeline,
//        counted vmcnt(4) (T3/T4), raw s_barrier, setprio (T5), XCD swizzle (T1),
//        both-sides 16B-granule LDS swizzle (T2-lite).
// agg1 / GEMM2 / agg2: all-bf16 intermediate dataflow, fp32 accumulation.

#define BN_EPS 1e-5f
#define GK 2000      // K of GEMM1
#define KP 2048      // padded K
#define NT1C 63      // ceil(2000/32) for cvt fallback path
#define NT1P 64      // 2048/32 for pure path
#define NT2 16       // 512/32

typedef __attribute__((ext_vector_type(8))) short bf16x8;
typedef __attribute__((ext_vector_type(4))) float f32x4;
typedef unsigned short u16x8 __attribute__((ext_vector_type(8)));

__device__ inline unsigned short f2bf(float f) {
    union { float f; unsigned u; } v; v.f = f;
    unsigned r = (v.u + 0x7fffu + ((v.u >> 16) & 1u)) >> 16;
    return (unsigned short)r;
}
__device__ inline float bf2f(unsigned short u) {
    union { unsigned u; float f; } v; v.u = ((unsigned)u) << 16;
    return v.f;
}

#define GLL16(gp, lp) __builtin_amdgcn_global_load_lds( \
    (const __attribute__((address_space(1))) void*)(gp), \
    (__attribute__((address_space(3))) void*)(lp), 16, 0, 0)

// ---------------- degree histogram ----------------
__global__ void count_kernel(const int* __restrict__ ei, int E, int* __restrict__ cnt) {
    int i = blockIdx.x * blockDim.x + threadIdx.x;
    if (i < E) atomicAdd(&cnt[ei[E + i]], 1);   // dst = ei[1][i]
}

// ---------------- exclusive scan over N counts (single block) ----------------
__global__ __launch_bounds__(1024) void scan_kernel(const int* __restrict__ cnt,
                                                    int* __restrict__ row_start, int n) {
    __shared__ int part[1024];
    int t = threadIdx.x;
    int chunk = (n + 1023) >> 10;
    int lo = t * chunk;
    int hi = lo + chunk; if (hi > n) hi = n;
    int s = 0;
    for (int i = lo; i < hi; ++i) s += cnt[i];
    part[t] = s;
    __syncthreads();
    for (int off = 1; off < 1024; off <<= 1) {
        int add = (t >= off) ? part[t - off] : 0;
        __syncthreads();
        part[t] += add;
        __syncthreads();
    }
    int run = (t == 0) ? 0 : part[t - 1];
    for (int i = lo; i < hi; ++i) { row_start[i] = run; run += cnt[i]; }
    if (t == 1023) row_start[n] = part[1023];
}

// ---------------- CSR fill (consumes cnt via atomicSub; cnt dead after) ---------
__global__ void fill_kernel(const int* __restrict__ ei, int E,
                            const int* __restrict__ row_start,
                            int* __restrict__ cnt, int* __restrict__ colidx) {
    int i = blockIdx.x * blockDim.x + threadIdx.x;
    if (i < E) {
        int d = ei[E + i];
        int p = atomicSub(&cnt[d], 1) - 1;
        colidx[row_start[d] + p] = ei[i];   // src
    }
}

// ---------------- x [M][2000] f32 -> xb [M][2048] bf16 (zero-padded) -------------
__global__ __launch_bounds__(256) void conv_kernel(const float* __restrict__ x,
                                                   unsigned short* __restrict__ xb) {
    int row = blockIdx.x;
    int k8 = threadIdx.x;   // group of 8; 250 valid, 6 pad
    unsigned short us[8];
    if (k8 < 250) {
        const float4* p = (const float4*)(x + (size_t)row * 2000 + k8 * 8);
        float4 v0 = p[0], v1 = p[1];
        us[0]=f2bf(v0.x); us[1]=f2bf(v0.y); us[2]=f2bf(v0.z); us[3]=f2bf(v0.w);
        us[4]=f2bf(v1.x); us[5]=f2bf(v1.y); us[6]=f2bf(v1.z); us[7]=f2bf(v1.w);
    } else {
#pragma unroll
        for (int j = 0; j < 8; ++j) us[j] = 0;
    }
    *(u16x8*)&xb[(size_t)row * 2048 + k8 * 8] = *(u16x8*)us;
}

// ---------------- BT1[1024][2048] bf16 = [W1l|W1r]^T, zero-padded ----------------
__global__ __launch_bounds__(256) void prep_bt(const float* __restrict__ W1l,
                                               const float* __restrict__ W1r,
                                               unsigned short* __restrict__ BT) {
    int idx = blockIdx.x * 256 + threadIdx.x;
    int c  = idx >> 8;
    int k0 = (idx & 255) << 3;
    const float* W = (c < 512) ? (W1l + c) : (W1r + (c - 512));
    unsigned short us[8];
#pragma unroll
    for (int j = 0; j < 8; ++j) {
        int k = k0 + j;
        float v = (k < GK) ? W[(size_t)k * 512] : 0.0f;
        us[j] = f2bf(v);
    }
    *(u16x8*)&BT[(size_t)c * KP + k0] = *(u16x8*)us;
}

// ---------------- BT2[128][512] bf16 = [W2l|W2r]^T ----------------
__global__ __launch_bounds__(256) void prep_bt2(const float* __restrict__ W2l,
                                                const float* __restrict__ W2r,
                                                unsigned short* __restrict__ BT2) {
    int idx = blockIdx.x * 256 + threadIdx.x;
    int c  = idx >> 6;
    int k0 = (idx & 63) << 3;
    const float* W = (c < 64) ? (W2l + c) : (W2r + (c - 64));
    unsigned short us[8];
#pragma unroll
    for (int j = 0; j < 8; ++j) us[j] = f2bf(W[(size_t)(k0 + j) * 64]);
    *(u16x8*)&BT2[(size_t)c * 512 + k0] = *(u16x8*)us;
}

// ---------------- GEMM1: Y = xb(bf16) @ BT^T — 256x256 tile, 3-ring pipeline -----
// 512 threads = 8 waves as 2(row) x 4(col); per-wave output 128x64 -> 32 MFMA/K-step.
// Ring of 3 LDS buffer-pairs (96 KB); stage(it+2) each iter; per iter:
// vmcnt(4) -> s_barrier -> 12x ds_read_b128 -> stage -> setprio(1) 32xMFMA setprio(0).
__global__ __launch_bounds__(512) void gemm1_256(
    const unsigned short* __restrict__ xb, int M,
    const unsigned short* __restrict__ BT,
    unsigned short* __restrict__ Y)
{
    __shared__ __align__(16) unsigned short As[3][8192];   // 256 rows x 32 k
    __shared__ __align__(16) unsigned short Bs[3][8192];   // 256 cols x 32 k

    const int t = threadIdx.x, wid = t >> 6, lane = t & 63;
    const int nbr = (M + 255) >> 8;          // 196 row-blocks
    const int nwg = nbr * 4;
    const int b   = blockIdx.x;
    // XCD-bijective swizzle (nwg % 8 == 0 when nbr even; else identity)
    int swz;
    if ((nwg & 7) == 0) swz = (b & 7) * (nwg >> 3) + (b >> 3);
    else swz = b;
    const int row0 = (swz >> 2) << 8;
    const int col0 = (swz & 3) << 8;

    // staging chunks c (16B each): c in {t, t+512}; row=c>>2, granule=c&3
    const int c0 = t, c1 = t + 512;
    const int g0 = ((c0 & 3) ^ ((c0 >> 2) & 3)) << 3;   // pre-swizzled src granule (elems)
    const int g1 = ((c1 & 3) ^ ((c1 >> 2) & 3)) << 3;
    int ra0 = row0 + (c0 >> 2); if (ra0 >= M) ra0 = M - 1;
    int ra1 = row0 + (c1 >> 2); if (ra1 >= M) ra1 = M - 1;
    const unsigned short* aS0 = xb + (size_t)ra0 * KP + g0;
    const unsigned short* aS1 = xb + (size_t)ra1 * KP + g1;
    const unsigned short* bS0 = BT + (size_t)(col0 + (c0 >> 2)) * KP + g0;
    const unsigned short* bS1 = BT + (size_t)(col0 + (c1 >> 2)) * KP + g1;

    const int wr = wid >> 2, wc = wid & 3;   // 2 x 4 wave grid
    const int fr16 = lane & 15;
    const int gswr = ((lane >> 4) ^ (fr16 & 3)) << 4;   // swizzled granule byte off

    f32x4 acc[8][4];
#pragma unroll
    for (int m = 0; m < 8; ++m)
#pragma unroll
        for (int n = 0; n < 4; ++n) acc[m][n] = (f32x4)0.0f;

#define STG(kt, buf) do {                                          \
        unsigned short* ab_ = &As[buf][0];                         \
        unsigned short* bb_ = &Bs[buf][0];                         \
        GLL16(aS0 + (size_t)(kt) * 32, ab_ + c0 * 8);              \
        GLL16(aS1 + (size_t)(kt) * 32, ab_ + c1 * 8);              \
        GLL16(bS0 + (size_t)(kt) * 32, bb_ + c0 * 8);              \
        GLL16(bS1 + (size_t)(kt) * 32, bb_ + c1 * 8);              \
    } while (0)

    // prologue: stage tiles 0 and 1 (8 loads/thread outstanding)
    STG(0, 0);
    STG(1, 1);

    int rb = 0;   // read buffer = it % 3
    for (int it = 0; it < NT1P; ++it) {
        // wait my 4 oldest loads (tile 'it'); tile it+1's 4 stay in flight.
        if (it == NT1P - 1) {
            asm volatile("s_waitcnt vmcnt(0)" ::: "memory");
        } else {
            asm volatile("s_waitcnt vmcnt(4)" ::: "memory");
        }
        __builtin_amdgcn_s_barrier();
        __builtin_amdgcn_sched_barrier(0);

        const char* Ab = (const char*)&As[rb][0];
        const char* Bb = (const char*)&Bs[rb][0];
        bf16x8 af[8], bfr[4];
#pragma unroll
        for (int m = 0; m < 8; ++m)
            af[m] = *(const bf16x8*)(Ab + ((wr * 128 + m * 16 + fr16) << 6) + gswr);
#pragma unroll
        for (int n = 0; n < 4; ++n)
            bfr[n] = *(const bf16x8*)(Bb + ((wc * 64 + n * 16 + fr16) << 6) + gswr);

        // stage tile it+2 into buf (it+2)%3 (all waves crossed barrier -> safe)
        if (it + 2 < NT1P) {
            int wb = rb + 2; if (wb >= 3) wb -= 3;
            STG(it + 2, wb);
        }

        __builtin_amdgcn_s_setprio(1);
#pragma unroll
        for (int m = 0; m < 8; ++m)
#pragma unroll
            for (int n = 0; n < 4; ++n)
                acc[m][n] = __builtin_amdgcn_mfma_f32_16x16x32_bf16(
                    af[m], bfr[n], acc[m][n], 0, 0, 0);
        __builtin_amdgcn_s_setprio(0);

        rb = (rb == 2) ? 0 : rb + 1;
    }
#undef STG

    const int crow = (lane >> 4) << 2;
#pragma unroll
    for (int m = 0; m < 8; ++m) {
        int rbase = row0 + wr * 128 + m * 16 + crow;
#pragma unroll
        for (int r = 0; r < 4; ++r) {
            int row = rbase + r;
            if (row < M) {
                unsigned short* Yp = Y + (size_t)row * 1024 + col0 + wc * 64 + fr16;
#pragma unroll
                for (int n = 0; n < 4; ++n)
                    Yp[n * 16] = f2bf(acc[m][n][r]);
            }
        }
    }
}

// ---------------- GEMM1 fallback (in-kernel f32->bf16, 128^2) ----------------
__global__ __launch_bounds__(256) void gemm1_cvt(
    const float* __restrict__ A, int M,
    const unsigned short* __restrict__ BT,
    unsigned short* __restrict__ Y)
{
    __shared__ __align__(16) unsigned short As[128][32];
    __shared__ __align__(16) unsigned short Bs[2][128][32];

    const int t    = threadIdx.x;
    const int wid  = t >> 6;
    const int lane = t & 63;
    const int nby = (M + 127) >> 7;
    const int b   = blockIdx.x;
    const int swz = (b & 7) * nby + (b >> 3);
    const int row0 = (swz >> 3) << 7;
    const int col0 = (swz & 7) << 7;

    const int ar  = t >> 1;
    const int akq = (t & 1) << 4;
    int garow = row0 + ar; if (garow >= M) garow = M - 1;
    const float* aptr = A + (size_t)garow * GK + akq;

    const int i0 = wid * 64 + lane;
    const unsigned short* bptr0 = BT + ((size_t)(col0 + (i0 >> 2)) * KP + ((i0 & 3) << 3));
    const unsigned short* bptr1 = bptr0 + (size_t)64 * KP;

    const int wr   = wid >> 1, wc = wid & 1;
    const int fr16 = lane & 15;
    const int kb8  = (lane >> 4) << 3;

    f32x4 acc[4][4];
#pragma unroll
    for (int m = 0; m < 4; ++m)
#pragma unroll
        for (int n = 0; n < 4; ++n) acc[m][n] = (f32x4)0.0f;

    GLL16(bptr0, &Bs[0][wid * 16][0]);
    GLL16(bptr1, &Bs[0][64 + wid * 16][0]);

    float frg[16];
    {
        const float4* p = (const float4*)aptr;
        float4 v0 = p[0], v1 = p[1], v2 = p[2], v3 = p[3];
        frg[0]=v0.x; frg[1]=v0.y; frg[2]=v0.z;  frg[3]=v0.w;
        frg[4]=v1.x; frg[5]=v1.y; frg[6]=v1.z;  frg[7]=v1.w;
        frg[8]=v2.x; frg[9]=v2.y; frg[10]=v2.z; frg[11]=v2.w;
        frg[12]=v3.x;frg[13]=v3.y;frg[14]=v3.z; frg[15]=v3.w;
    }

    int cur = 0;
    for (int it = 0; it < NT1C; ++it) {
        {
            unsigned short us[16];
#pragma unroll
            for (int j = 0; j < 16; ++j) us[j] = f2bf(frg[j]);
            *(u16x8*)&As[ar][akq]     = *(u16x8*)&us[0];
            *(u16x8*)&As[ar][akq + 8] = *(u16x8*)&us[8];
        }
        __syncthreads();

        if (it + 1 < NT1C) {
            int kb = (it + 1) * 32 + akq;
            if (kb < GK) {
                const float4* p = (const float4*)(aptr + (size_t)(it + 1) * 32);
                float4 v0 = p[0], v1 = p[1], v2 = p[2], v3 = p[3];
                frg[0]=v0.x; frg[1]=v0.y; frg[2]=v0.z;  frg[3]=v0.w;
                frg[4]=v1.x; frg[5]=v1.y; frg[6]=v1.z;  frg[7]=v1.w;
                frg[8]=v2.x; frg[9]=v2.y; frg[10]=v2.z; frg[11]=v2.w;
                frg[12]=v3.x;frg[13]=v3.y;frg[14]=v3.z; frg[15]=v3.w;
            } else {
#pragma unroll
                for (int j = 0; j < 16; ++j) frg[j] = 0.0f;
            }
            const unsigned short* bp = bptr0 + (size_t)(it + 1) * 32;
            GLL16(bp,                   &Bs[cur ^ 1][wid * 16][0]);
            GLL16(bp + (size_t)64 * KP, &Bs[cur ^ 1][64 + wid * 16][0]);
        }

        bf16x8 af[4], bfr[4];
#pragma unroll
        for (int m = 0; m < 4; ++m)
            af[m] = *(const bf16x8*)&As[wr * 64 + m * 16 + fr16][kb8];
#pragma unroll
        for (int n = 0; n < 4; ++n)
            bfr[n] = *(const bf16x8*)&Bs[cur][wc * 64 + n * 16 + fr16][kb8];
#pragma unroll
        for (int m = 0; m < 4; ++m)
#pragma unroll
            for (int n = 0; n < 4; ++n)
                acc[m][n] = __builtin_amdgcn_mfma_f32_16x16x32_bf16(
                    af[m], bfr[n], acc[m][n], 0, 0, 0);

        __syncthreads();
        cur ^= 1;
    }

    const int crow = (lane >> 4) << 2;
#pragma unroll
    for (int m = 0; m < 4; ++m) {
        int rbase = row0 + wr * 64 + m * 16 + crow;
#pragma unroll
        for (int r = 0; r < 4; ++r) {
            int row = rbase + r;
            if (row < M) {
                unsigned short* Yp = Y + (size_t)row * 1024 + col0 + wc * 64 + fr16;
#pragma unroll
                for (int n = 0; n < 4; ++n)
                    Yp[n * 16] = f2bf(acc[m][n][r]);
            }
        }
    }
}

// ---------------- agg1: mean-gather(Yl) + b1 + self(Yr) + BN + ReLU -> h (bf16) ----
__global__ __launch_bounds__(256) void agg1_kernel(
    const unsigned short* __restrict__ Y, unsigned short* __restrict__ Hh,
    const int* __restrict__ row_start, const int* __restrict__ colidx,
    const float* __restrict__ b1, const float* __restrict__ gamma,
    const float* __restrict__ beta, const float* __restrict__ mean,
    const float* __restrict__ var, int n)
{
    int wid  = (blockIdx.x * blockDim.x + threadIdx.x) >> 6;
    int lane = threadIdx.x & 63;
    if (wid >= n) return;
    int c0 = lane * 8;
    float sc[8], sh[8], bb[8];
#pragma unroll
    for (int j = 0; j < 8; ++j) {
        int c = c0 + j;
        sc[j] = gamma[c] * rsqrtf(var[c] + BN_EPS);
        sh[j] = beta[c] - mean[c] * sc[j];
        bb[j] = b1[c];
    }
    int s0 = row_start[wid], s1 = row_start[wid + 1];
    float acc[8] = {0, 0, 0, 0, 0, 0, 0, 0};
    for (int i = s0; i < s1; ++i) {
        int src = colidx[i];
        u16x8 v = *(const u16x8*)&Y[(size_t)src * 1024 + c0];
#pragma unroll
        for (int j = 0; j < 8; ++j) acc[j] += bf2f(v[j]);
    }
    float inv = 1.0f / fmaxf((float)(s1 - s0), 1.0f);
    u16x8 sv = *(const u16x8*)&Y[(size_t)wid * 1024 + 512 + c0];
    unsigned short o[8];
#pragma unroll
    for (int j = 0; j < 8; ++j) {
        float pre = acc[j] * inv + bb[j] + bf2f(sv[j]);
        float h = pre * sc[j] + sh[j];
        o[j] = f2bf(fmaxf(h, 0.0f));
    }
    *(u16x8*)&Hh[(size_t)wid * 512 + c0] = *(u16x8*)o;
}

// ---------------- GEMM2: U[M x 128](bf16) = h[M x 512](bf16) @ BT2^T ------------
__global__ __launch_bounds__(256) void gemm2_bf16(
    const unsigned short* __restrict__ Hh, int M,
    const unsigned short* __restrict__ BT2,
    unsigned short* __restrict__ U)
{
    __shared__ __align__(16) unsigned short As[2][128][32];
    __shared__ __align__(16) unsigned short Bs[2][128][32];

    const int t    = threadIdx.x;
    const int wid  = t >> 6;
    const int lane = t & 63;
    const int row0 = blockIdx.x << 7;

    const int c_lo = wid * 64 + lane;
    const int c_hi = c_lo + 256;
    int ra = row0 + (c_lo >> 2); if (ra >= M) ra = M - 1;
    int rb = row0 + (c_hi >> 2); if (rb >= M) rb = M - 1;
    const unsigned short* aSrc0 = Hh + (size_t)ra * 512 + ((c_lo & 3) << 3);
    const unsigned short* aSrc1 = Hh + (size_t)rb * 512 + ((c_hi & 3) << 3);
    const unsigned short* bSrc0 = BT2 + (size_t)(c_lo >> 2) * 512 + ((c_lo & 3) << 3);
    const unsigned short* bSrc1 = BT2 + (size_t)(c_hi >> 2) * 512 + ((c_hi & 3) << 3);

    const int wr   = wid >> 1, wc = wid & 1;
    const int fr16 = lane & 15;
    const int kb8  = (lane >> 4) << 3;

    f32x4 acc[4][4];
#pragma unroll
    for (int m = 0; m < 4; ++m)
#pragma unroll
        for (int n = 0; n < 4; ++n) acc[m][n] = (f32x4)0.0f;

#define STAGE2(kt, buf) do {                                                  \
        int ko = (kt) * 32;                                                   \
        GLL16(aSrc0 + ko, (unsigned short*)&As[buf][0][0] + (size_t)(wid * 64) * 8);        \
        GLL16(aSrc1 + ko, (unsigned short*)&As[buf][0][0] + (size_t)(256 + wid * 64) * 8);  \
        GLL16(bSrc0 + ko, (unsigned short*)&Bs[buf][0][0] + (size_t)(wid * 64) * 8);        \
        GLL16(bSrc1 + ko, (unsigned short*)&Bs[buf][0][0] + (size_t)(256 + wid * 64) * 8);  \
    } while (0)

    STAGE2(0, 0);
    int cur = 0;
    for (int it = 0; it < NT2; ++it) {
        __syncthreads();
        if (it + 1 < NT2) STAGE2(it + 1, cur ^ 1);

        bf16x8 af[4], bfr[4];
#pragma unroll
        for (int m = 0; m < 4; ++m)
            af[m] = *(const bf16x8*)&As[cur][wr * 64 + m * 16 + fr16][kb8];
#pragma unroll
        for (int n = 0; n < 4; ++n)
            bfr[n] = *(const bf16x8*)&Bs[cur][wc * 64 + n * 16 + fr16][kb8];
#pragma unroll
        for (int m = 0; m < 4; ++m)
#pragma unroll
            for (int n = 0; n < 4; ++n)
                acc[m][n] = __builtin_amdgcn_mfma_f32_16x16x32_bf16(
                    af[m], bfr[n], acc[m][n], 0, 0, 0);
        cur ^= 1;
    }
#undef STAGE2

    const int crow = (lane >> 4) << 2;
#pragma unroll
    for (int m = 0; m < 4; ++m) {
        int rbase = row0 + wr * 64 + m * 16 + crow;
#pragma unroll
        for (int r = 0; r < 4; ++r) {
            int row = rbase + r;
            if (row < M) {
                unsigned short* Up = U + (size_t)row * 128 + wc * 64 + fr16;
#pragma unroll
                for (int n = 0; n < 4; ++n)
                    Up[n * 16] = f2bf(acc[m][n][r]);
            }
        }
    }
}

// ---------------- agg2: mean-gather(Ul) + b2 + self(Ur) -> out (f32) ----------------
__global__ __launch_bounds__(256) void agg2_kernel(
    const unsigned short* __restrict__ U,
    const int* __restrict__ row_start, const int* __restrict__ colidx,
    const float* __restrict__ b2, float* __restrict__ out, int n)
{
    int wid  = (blockIdx.x * blockDim.x + threadIdx.x) >> 6;
    int lane = threadIdx.x & 63;
    if (wid >= n) return;
    int s0 = row_start[wid], s1 = row_start[wid + 1];
    float acc = 0.f;
    for (int i = s0; i < s1; ++i) {
        int src = colidx[i];
        acc += bf2f(U[(size_t)src * 128 + lane]);
    }
    float inv = 1.0f / fmaxf((float)(s1 - s0), 1.0f);
    float z = acc * inv + b2[lane] + bf2f(U[(size_t)wid * 128 + 64 + lane]);
    out[(size_t)wid * 64 + lane] = z;
}

extern "C" void kernel_launch(void* const* d_in, const int* in_sizes, int n_in,
                              void* d_out, int out_size, void* d_ws, size_t ws_size,
                              hipStream_t stream) {
    const float* x     = (const float*)d_in[0];
    const int*   ei    = (const int*)d_in[1];
    const float* W1l   = (const float*)d_in[2];
    const float* b1    = (const float*)d_in[3];
    const float* W1r   = (const float*)d_in[4];
    const float* gamma = (const float*)d_in[5];
    const float* beta  = (const float*)d_in[6];
    const float* mean  = (const float*)d_in[7];
    const float* var   = (const float*)d_in[8];
    const float* W2l   = (const float*)d_in[9];
    const float* b2    = (const float*)d_in[10];
    const float* W2r   = (const float*)d_in[11];
    float* out = (float*)d_out;

    const int N = in_sizes[0] / 2000;   // 50000
    const int E = in_sizes[1] / 2;      // 800000
    const int nby = (N + 127) / 128;

    char* ws = (char*)d_ws;

    // Primary layout: xb | Y | BT | BT2 | cnt | row_start | colidx
    //   (Hh aliases xb after gemm1; U aliases Y after agg1)
    size_t need = (size_t)N * KP * 2 + (size_t)N * 1024 * 2
                + (size_t)1024 * KP * 2 + (size_t)128 * 512 * 2
                + ((size_t)2 * N + 8 + (size_t)E) * 4;

    if (ws_size >= need) {
        unsigned short* xb  = (unsigned short*)ws;                 // N*2048 bf16
        unsigned short* Y   = xb + (size_t)N * KP;                 // N*1024 bf16
        unsigned short* BT  = Y + (size_t)N * 1024;                // 1024*2048 bf16
        unsigned short* BT2 = BT + (size_t)1024 * KP;              // 128*512 bf16
        int* cnt       = (int*)(BT2 + (size_t)128 * 512);
        int* row_start = cnt + N;
        int* colidx    = row_start + N + 4;                        // E
        unsigned short* Hh = xb;   // alias: xb dead after gemm1
        unsigned short* U  = Y;    // alias: Y dead after agg1

        hipMemsetAsync(cnt, 0, (size_t)N * sizeof(int), stream);

        prep_bt<<<1024, 256, 0, stream>>>(W1l, W1r, BT);
        prep_bt2<<<32, 256, 0, stream>>>(W2l, W2r, BT2);
        conv_kernel<<<N, 256, 0, stream>>>(x, xb);

        int eb = (E + 255) / 256;
        count_kernel<<<eb, 256, 0, stream>>>(ei, E, cnt);
        scan_kernel<<<1, 1024, 0, stream>>>(cnt, row_start, N);
        fill_kernel<<<eb, 256, 0, stream>>>(ei, E, row_start, cnt, colidx);

        int nbr = (N + 255) / 256;
        gemm1_256<<<nbr * 4, 512, 0, stream>>>(xb, N, BT, Y);
        agg1_kernel<<<(N + 3) / 4, 256, 0, stream>>>(
            Y, Hh, row_start, colidx, b1, gamma, beta, mean, var, N);
        gemm2_bf16<<<nby, 256, 0, stream>>>(Hh, N, BT2, U);
        agg2_kernel<<<(N + 3) / 4, 256, 0, stream>>>(
            U, row_start, colidx, b2, out, N);
    } else {
        // Fallback layout and kernels (128^2 cvt GEMM1)
        unsigned short* Y   = (unsigned short*)ws;                 // N*1024 bf16
        unsigned short* Hh  = Y + (size_t)N * 1024;                // N*512 bf16
        unsigned short* U   = Hh + (size_t)N * 512;                // N*128 bf16
        unsigned short* BT  = U + (size_t)N * 128;                 // 1024*2048 bf16
        unsigned short* BT2 = BT + (size_t)1024 * KP;              // 128*512 bf16
        int* cnt       = (int*)(BT2 + (size_t)128 * 512);
        int* row_start = cnt + N;
        int* colidx    = row_start + N + 4;

        hipMemsetAsync(cnt, 0, (size_t)N * sizeof(int), stream);

        prep_bt<<<1024, 256, 0, stream>>>(W1l, W1r, BT);
        prep_bt2<<<32, 256, 0, stream>>>(W2l, W2r, BT2);

        int eb = (E + 255) / 256;
        count_kernel<<<eb, 256, 0, stream>>>(ei, E, cnt);
        scan_kernel<<<1, 1024, 0, stream>>>(cnt, row_start, N);
        fill_kernel<<<eb, 256, 0, stream>>>(ei, E, row_start, cnt, colidx);

        gemm1_cvt<<<8 * nby, 256, 0, stream>>>(x, N, BT, Y);
        agg1_kernel<<<(N + 3) / 4, 256, 0, stream>>>(
            Y, Hh, row_start, colidx, b1, gamma, beta, mean, var, N);
        gemm2_bf16<<<nby, 256, 0, stream>>>(Hh, N, BT2, U);
        agg2_kernel<<<(N + 3) / 4, 256, 0, stream>>>(
            U, row_start, colidx, b2, out, N);
    }
}

// Round 7
// 765.355 us; speedup vs baseline: 3.9975x; 1.0075x over previous
//
#include <hip/hip_runtime.h>

// GraphSAGE encoder, restructured: aggregate AFTER linear maps.
//   N=50000, G=2000, E=800000, H=512, Z=64
// GEMM1: bf16 MFMA 256x256 tile, 8 waves (2x4 of 128x64), 3-ring LDS pipeline,
//        counted vmcnt(4) (T3/T4), raw s_barrier, setprio (T5), XCD swizzle (T1),
//        both-sides 16B-granule LDS swizzle with (row>>1)&3 XOR (2-way = free).
// agg1 / GEMM2 / agg2: all-bf16 intermediate dataflow, fp32 accumulation.

#define BN_EPS 1e-5f
#define GK 2000      // K of GEMM1
#define KP 2048      // padded K
#define NT1C 63      // ceil(2000/32) for cvt fallback path
#define NT1P 64      // 2048/32 for pure path
#define NT2 16       // 512/32

typedef __attribute__((ext_vector_type(8))) short bf16x8;
typedef __attribute__((ext_vector_type(4))) float f32x4;
typedef unsigned short u16x8 __attribute__((ext_vector_type(8)));

__device__ inline unsigned short f2bf(float f) {
    union { float f; unsigned u; } v; v.f = f;
    unsigned r = (v.u + 0x7fffu + ((v.u >> 16) & 1u)) >> 16;
    return (unsigned short)r;
}
__device__ inline float bf2f(unsigned short u) {
    union { unsigned u; float f; } v; v.u = ((unsigned)u) << 16;
    return v.f;
}

#define GLL16(gp, lp) __builtin_amdgcn_global_load_lds( \
    (const __attribute__((address_space(1))) void*)(gp), \
    (__attribute__((address_space(3))) void*)(lp), 16, 0, 0)

// ---------------- degree histogram ----------------
__global__ void count_kernel(const int* __restrict__ ei, int E, int* __restrict__ cnt) {
    int i = blockIdx.x * blockDim.x + threadIdx.x;
    if (i < E) atomicAdd(&cnt[ei[E + i]], 1);   // dst = ei[1][i]
}

// ---------------- exclusive scan over N counts (single block) ----------------
__global__ __launch_bounds__(1024) void scan_kernel(const int* __restrict__ cnt,
                                                    int* __restrict__ row_start, int n) {
    __shared__ int part[1024];
    int t = threadIdx.x;
    int chunk = (n + 1023) >> 10;
    int lo = t * chunk;
    int hi = lo + chunk; if (hi > n) hi = n;
    int s = 0;
    for (int i = lo; i < hi; ++i) s += cnt[i];
    part[t] = s;
    __syncthreads();
    for (int off = 1; off < 1024; off <<= 1) {
        int add = (t >= off) ? part[t - off] : 0;
        __syncthreads();
        part[t] += add;
        __syncthreads();
    }
    int run = (t == 0) ? 0 : part[t - 1];
    for (int i = lo; i < hi; ++i) { row_start[i] = run; run += cnt[i]; }
    if (t == 1023) row_start[n] = part[1023];
}

// ---------------- CSR fill (consumes cnt via atomicSub; cnt dead after) ---------
__global__ void fill_kernel(const int* __restrict__ ei, int E,
                            const int* __restrict__ row_start,
                            int* __restrict__ cnt, int* __restrict__ colidx) {
    int i = blockIdx.x * blockDim.x + threadIdx.x;
    if (i < E) {
        int d = ei[E + i];
        int p = atomicSub(&cnt[d], 1) - 1;
        colidx[row_start[d] + p] = ei[i];   // src
    }
}

// ---------------- x [M][2000] f32 -> xb [M][2048] bf16 (zero-padded) -------------
__global__ __launch_bounds__(256) void conv_kernel(const float* __restrict__ x,
                                                   unsigned short* __restrict__ xb) {
    int row = blockIdx.x;
    int k8 = threadIdx.x;   // group of 8; 250 valid, 6 pad
    unsigned short us[8];
    if (k8 < 250) {
        const float4* p = (const float4*)(x + (size_t)row * 2000 + k8 * 8);
        float4 v0 = p[0], v1 = p[1];
        us[0]=f2bf(v0.x); us[1]=f2bf(v0.y); us[2]=f2bf(v0.z); us[3]=f2bf(v0.w);
        us[4]=f2bf(v1.x); us[5]=f2bf(v1.y); us[6]=f2bf(v1.z); us[7]=f2bf(v1.w);
    } else {
#pragma unroll
        for (int j = 0; j < 8; ++j) us[j] = 0;
    }
    *(u16x8*)&xb[(size_t)row * 2048 + k8 * 8] = *(u16x8*)us;
}

// ---------------- BT1[1024][2048] bf16 = [W1l|W1r]^T, zero-padded ----------------
__global__ __launch_bounds__(256) void prep_bt(const float* __restrict__ W1l,
                                               const float* __restrict__ W1r,
                                               unsigned short* __restrict__ BT) {
    int idx = blockIdx.x * 256 + threadIdx.x;
    int c  = idx >> 8;
    int k0 = (idx & 255) << 3;
    const float* W = (c < 512) ? (W1l + c) : (W1r + (c - 512));
    unsigned short us[8];
#pragma unroll
    for (int j = 0; j < 8; ++j) {
        int k = k0 + j;
        float v = (k < GK) ? W[(size_t)k * 512] : 0.0f;
        us[j] = f2bf(v);
    }
    *(u16x8*)&BT[(size_t)c * KP + k0] = *(u16x8*)us;
}

// ---------------- BT2[128][512] bf16 = [W2l|W2r]^T ----------------
__global__ __launch_bounds__(256) void prep_bt2(const float* __restrict__ W2l,
                                                const float* __restrict__ W2r,
                                                unsigned short* __restrict__ BT2) {
    int idx = blockIdx.x * 256 + threadIdx.x;
    int c  = idx >> 6;
    int k0 = (idx & 63) << 3;
    const float* W = (c < 64) ? (W2l + c) : (W2r + (c - 64));
    unsigned short us[8];
#pragma unroll
    for (int j = 0; j < 8; ++j) us[j] = f2bf(W[(size_t)(k0 + j) * 64]);
    *(u16x8*)&BT2[(size_t)c * 512 + k0] = *(u16x8*)us;
}

// ---------------- GEMM1: Y = xb(bf16) @ BT^T — 256x256 tile, 3-ring pipeline -----
// 512 threads = 8 waves as 2(row) x 4(col); per-wave output 128x64 -> 32 MFMA/K-step.
// LDS swizzle: physical slot s of row r holds logical 16B-granule s ^ ((r>>1)&3).
// Within any 16-lane read phase this is <=2-way banked (free, m136); the old
// (r&3) XOR left rows==0 mod 4 on one bank quad (4-way, the 1.9e7 conflicts).
__global__ __launch_bounds__(512) void gemm1_256(
    const unsigned short* __restrict__ xb, int M,
    const unsigned short* __restrict__ BT,
    unsigned short* __restrict__ Y)
{
    __shared__ __align__(16) unsigned short As[3][8192];   // 256 rows x 32 k
    __shared__ __align__(16) unsigned short Bs[3][8192];   // 256 cols x 32 k

    const int t = threadIdx.x, wid = t >> 6, lane = t & 63;
    const int nbr = (M + 255) >> 8;          // 196 row-blocks
    const int nwg = nbr * 4;
    const int b   = blockIdx.x;
    // XCD-bijective swizzle (nwg % 8 == 0 when nbr even; else identity)
    int swz;
    if ((nwg & 7) == 0) swz = (b & 7) * (nwg >> 3) + (b >> 3);
    else swz = b;
    const int row0 = (swz >> 2) << 8;
    const int col0 = (swz & 3) << 8;

    // staging chunks c (16B each): c in {t, t+512}; row=c>>2, slot=c&3
    // source granule = slot ^ ((row>>1)&3) = (c&3) ^ ((c>>3)&3)
    const int c0 = t, c1 = t + 512;
    const int g0 = ((c0 & 3) ^ ((c0 >> 3) & 3)) << 3;   // elems
    const int g1 = ((c1 & 3) ^ ((c1 >> 3) & 3)) << 3;
    int ra0 = row0 + (c0 >> 2); if (ra0 >= M) ra0 = M - 1;
    int ra1 = row0 + (c1 >> 2); if (ra1 >= M) ra1 = M - 1;
    const unsigned short* aS0 = xb + (size_t)ra0 * KP + g0;
    const unsigned short* aS1 = xb + (size_t)ra1 * KP + g1;
    const unsigned short* bS0 = BT + (size_t)(col0 + (c0 >> 2)) * KP + g0;
    const unsigned short* bS1 = BT + (size_t)(col0 + (c1 >> 2)) * KP + g1;

    const int wr = wid >> 2, wc = wid & 3;   // 2 x 4 wave grid
    const int fr16 = lane & 15;
    // read: logical granule lane>>4 of row (..+fr16); (row>>1)&3 == (fr16>>1)&3
    const int gswr = ((lane >> 4) ^ ((fr16 >> 1) & 3)) << 4;   // bytes

    f32x4 acc[8][4];
#pragma unroll
    for (int m = 0; m < 8; ++m)
#pragma unroll
        for (int n = 0; n < 4; ++n) acc[m][n] = (f32x4)0.0f;

#define STG(kt, buf) do {                                          \
        unsigned short* ab_ = &As[buf][0];                         \
        unsigned short* bb_ = &Bs[buf][0];                         \
        GLL16(aS0 + (size_t)(kt) * 32, ab_ + c0 * 8);              \
        GLL16(aS1 + (size_t)(kt) * 32, ab_ + c1 * 8);              \
        GLL16(bS0 + (size_t)(kt) * 32, bb_ + c0 * 8);              \
        GLL16(bS1 + (size_t)(kt) * 32, bb_ + c1 * 8);              \
    } while (0)

    // prologue: stage tiles 0 and 1 (8 loads/thread outstanding)
    STG(0, 0);
    STG(1, 1);

    int rb = 0;   // read buffer = it % 3
    for (int it = 0; it < NT1P; ++it) {
        // wait my 4 oldest loads (tile 'it'); tile it+1's 4 stay in flight.
        if (it == NT1P - 1) {
            asm volatile("s_waitcnt vmcnt(0)" ::: "memory");
        } else {
            asm volatile("s_waitcnt vmcnt(4)" ::: "memory");
        }
        __builtin_amdgcn_s_barrier();
        __builtin_amdgcn_sched_barrier(0);

        const char* Ab = (const char*)&As[rb][0];
        const char* Bb = (const char*)&Bs[rb][0];
        bf16x8 af[8], bfr[4];
#pragma unroll
        for (int m = 0; m < 8; ++m)
            af[m] = *(const bf16x8*)(Ab + ((wr * 128 + m * 16 + fr16) << 6) + gswr);
#pragma unroll
        for (int n = 0; n < 4; ++n)
            bfr[n] = *(const bf16x8*)(Bb + ((wc * 64 + n * 16 + fr16) << 6) + gswr);

        // stage tile it+2 into buf (it+2)%3 (all waves crossed barrier -> safe)
        if (it + 2 < NT1P) {
            int wb = rb + 2; if (wb >= 3) wb -= 3;
            STG(it + 2, wb);
        }

        __builtin_amdgcn_s_setprio(1);
#pragma unroll
        for (int m = 0; m < 8; ++m)
#pragma unroll
            for (int n = 0; n < 4; ++n)
                acc[m][n] = __builtin_amdgcn_mfma_f32_16x16x32_bf16(
                    af[m], bfr[n], acc[m][n], 0, 0, 0);
        __builtin_amdgcn_s_setprio(0);

        rb = (rb == 2) ? 0 : rb + 1;
    }
#undef STG

    const int crow = (lane >> 4) << 2;
#pragma unroll
    for (int m = 0; m < 8; ++m) {
        int rbase = row0 + wr * 128 + m * 16 + crow;
#pragma unroll
        for (int r = 0; r < 4; ++r) {
            int row = rbase + r;
            if (row < M) {
                unsigned short* Yp = Y + (size_t)row * 1024 + col0 + wc * 64 + fr16;
#pragma unroll
                for (int n = 0; n < 4; ++n)
                    Yp[n * 16] = f2bf(acc[m][n][r]);
            }
        }
    }
}

// ---------------- GEMM1 fallback (in-kernel f32->bf16, 128^2) ----------------
__global__ __launch_bounds__(256) void gemm1_cvt(
    const float* __restrict__ A, int M,
    const unsigned short* __restrict__ BT,
    unsigned short* __restrict__ Y)
{
    __shared__ __align__(16) unsigned short As[128][32];
    __shared__ __align__(16) unsigned short Bs[2][128][32];

    const int t    = threadIdx.x;
    const int wid  = t >> 6;
    const int lane = t & 63;
    const int nby = (M + 127) >> 7;
    const int b   = blockIdx.x;
    const int swz = (b & 7) * nby + (b >> 3);
    const int row0 = (swz >> 3) << 7;
    const int col0 = (swz & 7) << 7;

    const int ar  = t >> 1;
    const int akq = (t & 1) << 4;
    int garow = row0 + ar; if (garow >= M) garow = M - 1;
    const float* aptr = A + (size_t)garow * GK + akq;

    const int i0 = wid * 64 + lane;
    const unsigned short* bptr0 = BT + ((size_t)(col0 + (i0 >> 2)) * KP + ((i0 & 3) << 3));
    const unsigned short* bptr1 = bptr0 + (size_t)64 * KP;

    const int wr   = wid >> 1, wc = wid & 1;
    const int fr16 = lane & 15;
    const int kb8  = (lane >> 4) << 3;

    f32x4 acc[4][4];
#pragma unroll
    for (int m = 0; m < 4; ++m)
#pragma unroll
        for (int n = 0; n < 4; ++n) acc[m][n] = (f32x4)0.0f;

    GLL16(bptr0, &Bs[0][wid * 16][0]);
    GLL16(bptr1, &Bs[0][64 + wid * 16][0]);

    float frg[16];
    {
        const float4* p = (const float4*)aptr;
        float4 v0 = p[0], v1 = p[1], v2 = p[2], v3 = p[3];
        frg[0]=v0.x; frg[1]=v0.y; frg[2]=v0.z;  frg[3]=v0.w;
        frg[4]=v1.x; frg[5]=v1.y; frg[6]=v1.z;  frg[7]=v1.w;
        frg[8]=v2.x; frg[9]=v2.y; frg[10]=v2.z; frg[11]=v2.w;
        frg[12]=v3.x;frg[13]=v3.y;frg[14]=v3.z; frg[15]=v3.w;
    }

    int cur = 0;
    for (int it = 0; it < NT1C; ++it) {
        {
            unsigned short us[16];
#pragma unroll
            for (int j = 0; j < 16; ++j) us[j] = f2bf(frg[j]);
            *(u16x8*)&As[ar][akq]     = *(u16x8*)&us[0];
            *(u16x8*)&As[ar][akq + 8] = *(u16x8*)&us[8];
        }
        __syncthreads();

        if (it + 1 < NT1C) {
            int kb = (it + 1) * 32 + akq;
            if (kb < GK) {
                const float4* p = (const float4*)(aptr + (size_t)(it + 1) * 32);
                float4 v0 = p[0], v1 = p[1], v2 = p[2], v3 = p[3];
                frg[0]=v0.x; frg[1]=v0.y; frg[2]=v0.z;  frg[3]=v0.w;
                frg[4]=v1.x; frg[5]=v1.y; frg[6]=v1.z;  frg[7]=v1.w;
                frg[8]=v2.x; frg[9]=v2.y; frg[10]=v2.z; frg[11]=v2.w;
                frg[12]=v3.x;frg[13]=v3.y;frg[14]=v3.z; frg[15]=v3.w;
            } else {
#pragma unroll
                for (int j = 0; j < 16; ++j) frg[j] = 0.0f;
            }
            const unsigned short* bp = bptr0 + (size_t)(it + 1) * 32;
            GLL16(bp,                   &Bs[cur ^ 1][wid * 16][0]);
            GLL16(bp + (size_t)64 * KP, &Bs[cur ^ 1][64 + wid * 16][0]);
        }

        bf16x8 af[4], bfr[4];
#pragma unroll
        for (int m = 0; m < 4; ++m)
            af[m] = *(const bf16x8*)&As[wr * 64 + m * 16 + fr16][kb8];
#pragma unroll
        for (int n = 0; n < 4; ++n)
            bfr[n] = *(const bf16x8*)&Bs[cur][wc * 64 + n * 16 + fr16][kb8];
#pragma unroll
        for (int m = 0; m < 4; ++m)
#pragma unroll
            for (int n = 0; n < 4; ++n)
                acc[m][n] = __builtin_amdgcn_mfma_f32_16x16x32_bf16(
                    af[m], bfr[n], acc[m][n], 0, 0, 0);

        __syncthreads();
        cur ^= 1;
    }

    const int crow = (lane >> 4) << 2;
#pragma unroll
    for (int m = 0; m < 4; ++m) {
        int rbase = row0 + wr * 64 + m * 16 + crow;
#pragma unroll
        for (int r = 0; r < 4; ++r) {
            int row = rbase + r;
            if (row < M) {
                unsigned short* Yp = Y + (size_t)row * 1024 + col0 + wc * 64 + fr16;
#pragma unroll
                for (int n = 0; n < 4; ++n)
                    Yp[n * 16] = f2bf(acc[m][n][r]);
            }
        }
    }
}

// ---------------- agg1: mean-gather(Yl) + b1 + self(Yr) + BN + ReLU -> h (bf16) ----
__global__ __launch_bounds__(256) void agg1_kernel(
    const unsigned short* __restrict__ Y, unsigned short* __restrict__ Hh,
    const int* __restrict__ row_start, const int* __restrict__ colidx,
    const float* __restrict__ b1, const float* __restrict__ gamma,
    const float* __restrict__ beta, const float* __restrict__ mean,
    const float* __restrict__ var, int n)
{
    int wid  = (blockIdx.x * blockDim.x + threadIdx.x) >> 6;
    int lane = threadIdx.x & 63;
    if (wid >= n) return;
    int c0 = lane * 8;
    float sc[8], sh[8], bb[8];
#pragma unroll
    for (int j = 0; j < 8; ++j) {
        int c = c0 + j;
        sc[j] = gamma[c] * rsqrtf(var[c] + BN_EPS);
        sh[j] = beta[c] - mean[c] * sc[j];
        bb[j] = b1[c];
    }
    int s0 = row_start[wid], s1 = row_start[wid + 1];
    float acc[8] = {0, 0, 0, 0, 0, 0, 0, 0};
    for (int i = s0; i < s1; ++i) {
        int src = colidx[i];
        u16x8 v = *(const u16x8*)&Y[(size_t)src * 1024 + c0];
#pragma unroll
        for (int j = 0; j < 8; ++j) acc[j] += bf2f(v[j]);
    }
    float inv = 1.0f / fmaxf((float)(s1 - s0), 1.0f);
    u16x8 sv = *(const u16x8*)&Y[(size_t)wid * 1024 + 512 + c0];
    unsigned short o[8];
#pragma unroll
    for (int j = 0; j < 8; ++j) {
        float pre = acc[j] * inv + bb[j] + bf2f(sv[j]);
        float h = pre * sc[j] + sh[j];
        o[j] = f2bf(fmaxf(h, 0.0f));
    }
    *(u16x8*)&Hh[(size_t)wid * 512 + c0] = *(u16x8*)o;
}

// ---------------- GEMM2: U[M x 128](bf16) = h[M x 512](bf16) @ BT2^T ------------
// Same granule swizzle as gemm1 (was unswizzled: 8-way read conflict).
__global__ __launch_bounds__(256) void gemm2_bf16(
    const unsigned short* __restrict__ Hh, int M,
    const unsigned short* __restrict__ BT2,
    unsigned short* __restrict__ U)
{
    __shared__ __align__(16) unsigned short As[2][128][32];
    __shared__ __align__(16) unsigned short Bs[2][128][32];

    const int t    = threadIdx.x;
    const int wid  = t >> 6;
    const int lane = t & 63;
    const int row0 = blockIdx.x << 7;

    const int c_lo = wid * 64 + lane;
    const int c_hi = c_lo + 256;
    const int s_lo = ((c_lo & 3) ^ ((c_lo >> 3) & 3)) << 3;   // src granule (elems)
    const int s_hi = ((c_hi & 3) ^ ((c_hi >> 3) & 3)) << 3;
    int ra = row0 + (c_lo >> 2); if (ra >= M) ra = M - 1;
    int rbw = row0 + (c_hi >> 2); if (rbw >= M) rbw = M - 1;
    const unsigned short* aSrc0 = Hh + (size_t)ra * 512 + s_lo;
    const unsigned short* aSrc1 = Hh + (size_t)rbw * 512 + s_hi;
    const unsigned short* bSrc0 = BT2 + (size_t)(c_lo >> 2) * 512 + s_lo;
    const unsigned short* bSrc1 = BT2 + (size_t)(c_hi >> 2) * 512 + s_hi;

    const int wr   = wid >> 1, wc = wid & 1;
    const int fr16 = lane & 15;
    const int gsw2 = ((lane >> 4) ^ ((fr16 >> 1) & 3)) << 4;  // read byte offset

    f32x4 acc[4][4];
#pragma unroll
    for (int m = 0; m < 4; ++m)
#pragma unroll
        for (int n = 0; n < 4; ++n) acc[m][n] = (f32x4)0.0f;

#define STAGE2(kt, buf) do {                                                  \
        int ko = (kt) * 32;                                                   \
        GLL16(aSrc0 + ko, (unsigned short*)&As[buf][0][0] + (size_t)c_lo * 8);  \
        GLL16(aSrc1 + ko, (unsigned short*)&As[buf][0][0] + (size_t)c_hi * 8);  \
        GLL16(bSrc0 + ko, (unsigned short*)&Bs[buf][0][0] + (size_t)c_lo * 8);  \
        GLL16(bSrc1 + ko, (unsigned short*)&Bs[buf][0][0] + (size_t)c_hi * 8);  \
    } while (0)

    STAGE2(0, 0);
    int cur = 0;
    for (int it = 0; it < NT2; ++it) {
        __syncthreads();
        if (it + 1 < NT2) STAGE2(it + 1, cur ^ 1);

        const char* Ab = (const char*)&As[cur][0][0];
        const char* Bb = (const char*)&Bs[cur][0][0];
        bf16x8 af[4], bfr[4];
#pragma unroll
        for (int m = 0; m < 4; ++m)
            af[m] = *(const bf16x8*)(Ab + ((wr * 64 + m * 16 + fr16) << 6) + gsw2);
#pragma unroll
        for (int n = 0; n < 4; ++n)
            bfr[n] = *(const bf16x8*)(Bb + ((wc * 64 + n * 16 + fr16) << 6) + gsw2);
#pragma unroll
        for (int m = 0; m < 4; ++m)
#pragma unroll
            for (int n = 0; n < 4; ++n)
                acc[m][n] = __builtin_amdgcn_mfma_f32_16x16x32_bf16(
                    af[m], bfr[n], acc[m][n], 0, 0, 0);
        cur ^= 1;
    }
#undef STAGE2

    const int crow = (lane >> 4) << 2;
#pragma unroll
    for (int m = 0; m < 4; ++m) {
        int rbase = row0 + wr * 64 + m * 16 + crow;
#pragma unroll
        for (int r = 0; r < 4; ++r) {
            int row = rbase + r;
            if (row < M) {
                unsigned short* Up = U + (size_t)row * 128 + wc * 64 + fr16;
#pragma unroll
                for (int n = 0; n < 4; ++n)
                    Up[n * 16] = f2bf(acc[m][n][r]);
            }
        }
    }
}

// ---------------- agg2: mean-gather(Ul) + b2 + self(Ur) -> out (f32) ----------------
__global__ __launch_bounds__(256) void agg2_kernel(
    const unsigned short* __restrict__ U,
    const int* __restrict__ row_start, const int* __restrict__ colidx,
    const float* __restrict__ b2, float* __restrict__ out, int n)
{
    int wid  = (blockIdx.x * blockDim.x + threadIdx.x) >> 6;
    int lane = threadIdx.x & 63;
    if (wid >= n) return;
    int s0 = row_start[wid], s1 = row_start[wid + 1];
    float acc = 0.f;
    for (int i = s0; i < s1; ++i) {
        int src = colidx[i];
        acc += bf2f(U[(size_t)src * 128 + lane]);
    }
    float inv = 1.0f / fmaxf((float)(s1 - s0), 1.0f);
    float z = acc * inv + b2[lane] + bf2f(U[(size_t)wid * 128 + 64 + lane]);
    out[(size_t)wid * 64 + lane] = z;
}

extern "C" void kernel_launch(void* const* d_in, const int* in_sizes, int n_in,
                              void* d_out, int out_size, void* d_ws, size_t ws_size,
                              hipStream_t stream) {
    const float* x     = (const float*)d_in[0];
    const int*   ei    = (const int*)d_in[1];
    const float* W1l   = (const float*)d_in[2];
    const float* b1    = (const float*)d_in[3];
    const float* W1r   = (const float*)d_in[4];
    const float* gamma = (const float*)d_in[5];
    const float* beta  = (const float*)d_in[6];
    const float* mean  = (const float*)d_in[7];
    const float* var   = (const float*)d_in[8];
    const float* W2l   = (const float*)d_in[9];
    const float* b2    = (const float*)d_in[10];
    const float* W2r   = (const float*)d_in[11];
    float* out = (float*)d_out;

    const int N = in_sizes[0] / 2000;   // 50000
    const int E = in_sizes[1] / 2;      // 800000
    const int nby = (N + 127) / 128;

    char* ws = (char*)d_ws;

    // Primary layout: xb | Y | BT | BT2 | cnt | row_start | colidx
    //   (Hh aliases xb after gemm1; U aliases Y after agg1)
    size_t need = (size_t)N * KP * 2 + (size_t)N * 1024 * 2
                + (size_t)1024 * KP * 2 + (size_t)128 * 512 * 2
                + ((size_t)2 * N + 8 + (size_t)E) * 4;

    if (ws_size >= need) {
        unsigned short* xb  = (unsigned short*)ws;                 // N*2048 bf16
        unsigned short* Y   = xb + (size_t)N * KP;                 // N*1024 bf16
        unsigned short* BT  = Y + (size_t)N * 1024;                // 1024*2048 bf16
        unsigned short* BT2 = BT + (size_t)1024 * KP;              // 128*512 bf16
        int* cnt       = (int*)(BT2 + (size_t)128 * 512);
        int* row_start = cnt + N;
        int* colidx    = row_start + N + 4;                        // E
        unsigned short* Hh = xb;   // alias: xb dead after gemm1
        unsigned short* U  = Y;    // alias: Y dead after agg1

        hipMemsetAsync(cnt, 0, (size_t)N * sizeof(int), stream);

        prep_bt<<<1024, 256, 0, stream>>>(W1l, W1r, BT);
        prep_bt2<<<32, 256, 0, stream>>>(W2l, W2r, BT2);
        conv_kernel<<<N, 256, 0, stream>>>(x, xb);

        int eb = (E + 255) / 256;
        count_kernel<<<eb, 256, 0, stream>>>(ei, E, cnt);
        scan_kernel<<<1, 1024, 0, stream>>>(cnt, row_start, N);
        fill_kernel<<<eb, 256, 0, stream>>>(ei, E, row_start, cnt, colidx);

        int nbr = (N + 255) / 256;
        gemm1_256<<<nbr * 4, 512, 0, stream>>>(xb, N, BT, Y);
        agg1_kernel<<<(N + 3) / 4, 256, 0, stream>>>(
            Y, Hh, row_start, colidx, b1, gamma, beta, mean, var, N);
        gemm2_bf16<<<nby, 256, 0, stream>>>(Hh, N, BT2, U);
        agg2_kernel<<<(N + 3) / 4, 256, 0, stream>>>(
            U, row_start, colidx, b2, out, N);
    } else {
        // Fallback layout and kernels (128^2 cvt GEMM1; gemm2 uses swizzled path)
        unsigned short* Y   = (unsigned short*)ws;                 // N*1024 bf16
        unsigned short* Hh  = Y + (size_t)N * 1024;                // N*512 bf16
        unsigned short* U   = Hh + (size_t)N * 512;                // N*128 bf16
        unsigned short* BT  = U + (size_t)N * 128;                 // 1024*2048 bf16
        unsigned short* BT2 = BT + (size_t)1024 * KP;              // 128*512 bf16
        int* cnt       = (int*)(BT2 + (size_t)128 * 512);
        int* row_start = cnt + N;
        int* colidx    = row_start + N + 4;

        hipMemsetAsync(cnt, 0, (size_t)N * sizeof(int), stream);

        prep_bt<<<1024, 256, 0, stream>>>(W1l, W1r, BT);
        prep_bt2<<<32, 256, 0, stream>>>(W2l, W2r, BT2);

        int eb = (E + 255) / 256;
        count_kernel<<<eb, 256, 0, stream>>>(ei, E, cnt);
        scan_kernel<<<1, 1024, 0, stream>>>(cnt, row_start, N);
        fill_kernel<<<eb, 256, 0, stream>>>(ei, E, row_start, cnt, colidx);

        gemm1_cvt<<<8 * nby, 256, 0, stream>>>(x, N, BT, Y);
        agg1_kernel<<<(N + 3) / 4, 256, 0, stream>>>(
            Y, Hh, row_start, colidx, b1, gamma, beta, mean, var, N);
        gemm2_bf16<<<nby, 256, 0, stream>>>(Hh, N, BT2, U);
        agg2_kernel<<<(N + 3) / 4, 256, 0, stream>>>(
            U, row_start, colidx, b2, out, N);
    }
}